// Round 7
// baseline (2454.199 us; speedup 1.0000x reference)
//
#include <hip/hip_runtime.h>

#define NN 50000
#define NE 800000
#define DD 128
#define LN_EPS 1e-5f
#define NBLK 12500   // node blocks per slice (4 nodes/block)

typedef __attribute__((ext_vector_type(8))) short v8s;    // 8 bf16
typedef __attribute__((ext_vector_type(4))) float f32x4;  // MFMA acc

__device__ __forceinline__ float leakyf(float x){ return x > 0.f ? x : 0.05f*x; }
__device__ __forceinline__ short f2bf(float f){
  unsigned u = __float_as_uint(f);
  u = (u + 0x7fffu + ((u >> 16) & 1u)) >> 16;   // RNE
  return (short)u;
}
__device__ __forceinline__ float bf2f(unsigned short h){
  return __uint_as_float(((unsigned)h) << 16);
}
// split fp32 -> {hi, lo}: hi = truncated top-16 (cheap), lo = RNE(residual).
__device__ __forceinline__ short2 f2bf2v(float v){
  unsigned u = __float_as_uint(v);
  short hi = (short)(u >> 16);
  float lo = v - __uint_as_float(u & 0xffff0000u);
  return make_short2(hi, f2bf(lo));
}

// ---------------------------------------------------------------------------
// Pack fp32 W[K][128] -> two bf16 planes Wh/Wl, layout [(k>>3)*128 + n][k&7]
// ---------------------------------------------------------------------------
__global__ void pack_w_kernel(const float* __restrict__ W, short* __restrict__ Wh,
                              short* __restrict__ Wl, int K, int Kp)
{
  int idx = blockIdx.x*256 + threadIdx.x;
  if (idx >= Kp*128) return;
  int k = idx >> 7, n = idx & 127;
  float v = (k < K) ? W[k*128 + n] : 0.f;
  short2 t = f2bf2v(v);
  size_t o = ((size_t)(k >> 3)*128 + n)*8 + (k & 7);
  Wh[o] = t.x; Wl[o] = t.y;
}

#define MFMA3(ah, al, bh, bl, ac) \
  ac = __builtin_amdgcn_mfma_f32_16x16x32_bf16(al, bh, ac, 0,0,0); \
  ac = __builtin_amdgcn_mfma_f32_16x16x32_bf16(ah, bl, ac, 0,0,0); \
  ac = __builtin_amdgcn_mfma_f32_16x16x32_bf16(ah, bh, ac, 0,0,0);

#define SPLIT8(f0, f1, h, l) { \
  short2 t0 = f2bf2v(f0.x), t1 = f2bf2v(f0.y), t2 = f2bf2v(f0.z), t3 = f2bf2v(f0.w); \
  short2 t4 = f2bf2v(f1.x), t5 = f2bf2v(f1.y), t6 = f2bf2v(f1.z), t7 = f2bf2v(f1.w); \
  h[0]=t0.x; l[0]=t0.y; h[1]=t1.x; l[1]=t1.y; h[2]=t2.x; l[2]=t2.y; h[3]=t3.x; l[3]=t3.y; \
  h[4]=t4.x; l[4]=t4.y; h[5]=t5.x; l[5]=t5.y; h[6]=t6.x; l[6]=t6.y; h[7]=t7.x; l[7]=t7.y; }

// ---------------------------------------------------------------------------
// 3-layer MLP + LayerNorm, split-bf16 3-MFMA.
// SCATTER (edge encoder): edges processed in src-sorted order via eperm,
// output seg-reduced per src in LDS, one atomicAdd per (segment, col).
// ---------------------------------------------------------------------------
template<int IN_W, bool SCATTER>
__global__ __launch_bounds__(256)
void mlp_mfma_kernel(const float* __restrict__ x, int nrows,
                     const short* __restrict__ W1h, const short* __restrict__ W1l,
                     const float* __restrict__ b1,
                     const short* __restrict__ W2h, const short* __restrict__ W2l,
                     const float* __restrict__ b2,
                     const short* __restrict__ W3h, const short* __restrict__ W3l,
                     const float* __restrict__ b3,
                     const float* __restrict__ g, const float* __restrict__ bb,
                     float* __restrict__ out,
                     const int* __restrict__ sidx,   // src-sorted src values
                     const int* __restrict__ eperm)  // sorted pos -> edge id
{
  constexpr int L1K = (IN_W + 31) / 32;
  __shared__ __align__(16) short Hboth[2*128*136];
  short* Hh = Hboth;
  short* Hl = Hboth + 128*136;
  float* Hf = (float*)Hboth;                          // stride 132 in reduce phase
  __shared__ float lnS[128][2], lnQ[128][2];
  __shared__ int sidx_s[128];
  __shared__ int eperm_s[128];

  const int tid  = threadIdx.x;
  const int lane = tid & 63, wave = tid >> 6;
  const int wr = wave >> 1, wc = wave & 1;
  const int quad = lane >> 4, low = lane & 15;
  const int row0 = blockIdx.x * 128;

  if (SCATTER) {
    if (tid < 128) {
      sidx_s[tid]  = sidx[row0 + tid];   // NE % 128 == 0
      eperm_s[tid] = eperm[row0 + tid];
    }
    __syncthreads();
  }

  f32x4 acc[4][4];

  // ---------------- layer 1 ----------------
  #pragma unroll
  for (int tm=0;tm<4;tm++)
    #pragma unroll
    for (int tn=0;tn<4;tn++) acc[tm][tn] = (f32x4)0.f;

  for (int ks = 0; ks < L1K; ks++) {
    v8s ah[4], al[4], bh[4], bl[4];
    #pragma unroll
    for (int tm=0;tm<4;tm++) {
      int lr = wr*64 + tm*16 + low;
      v8s h = (v8s)0, l = (v8s)0;
      if (SCATTER && IN_W == 4) {
        if (quad == 0) {
          int e = eperm_s[lr];
          float4 f = ((const float4*)x)[e];
          short2 t0 = f2bf2v(f.x), t1 = f2bf2v(f.y), t2 = f2bf2v(f.z), t3 = f2bf2v(f.w);
          h[0]=t0.x; l[0]=t0.y; h[1]=t1.x; l[1]=t1.y;
          h[2]=t2.x; l[2]=t2.y; h[3]=t3.x; l[3]=t3.y;
        }
      } else if (IN_W % 32 == 0) {
        int r = row0 + lr;
        if (r < nrows) {
          const float* p = x + (size_t)r*IN_W + ks*32 + quad*8;
          float4 f0 = *(const float4*)p;
          float4 f1 = *(const float4*)(p + 4);
          SPLIT8(f0, f1, h, l);
        }
      } else {
        int r = row0 + lr;
        #pragma unroll
        for (int j=0;j<8;j++) {
          int k = ks*32 + quad*8 + j;
          if (k < IN_W && r < nrows) {
            short2 t = f2bf2v(x[(size_t)r*IN_W + k]);
            h[j] = t.x; l[j] = t.y;
          }
        }
      }
      ah[tm] = h; al[tm] = l;
    }
    #pragma unroll
    for (int tn=0;tn<4;tn++) {
      size_t o = ((size_t)(ks*4+quad)*128 + wc*64 + tn*16 + low)*8;
      bh[tn] = *(const v8s*)(W1h + o);
      bl[tn] = *(const v8s*)(W1l + o);
    }
    #pragma unroll
    for (int tm=0;tm<4;tm++)
      #pragma unroll
      for (int tn=0;tn<4;tn++) { MFMA3(ah[tm], al[tm], bh[tn], bl[tn], acc[tm][tn]); }
  }
  if (SCATTER) __syncthreads();
  #pragma unroll
  for (int tn=0;tn<4;tn++) {
    float bv = b1[wc*64 + tn*16 + low];
    #pragma unroll
    for (int tm=0;tm<4;tm++)
      #pragma unroll
      for (int i=0;i<4;i++) {
        int idx = (wr*64+tm*16+quad*4+i)*136 + wc*64+tn*16+low;
        short2 t = f2bf2v(leakyf(acc[tm][tn][i] + bv));
        Hh[idx] = t.x; Hl[idx] = t.y;
      }
  }
  __syncthreads();

  // ---------------- layer 2 ----------------
  #pragma unroll
  for (int tm=0;tm<4;tm++)
    #pragma unroll
    for (int tn=0;tn<4;tn++) acc[tm][tn] = (f32x4)0.f;
  #pragma unroll
  for (int ks=0;ks<4;ks++) {
    v8s ah[4], al[4], bh[4], bl[4];
    #pragma unroll
    for (int tm=0;tm<4;tm++) {
      int idx = (wr*64+tm*16+low)*136 + ks*32 + quad*8;
      ah[tm] = *(const v8s*)&Hh[idx];
      al[tm] = *(const v8s*)&Hl[idx];
    }
    #pragma unroll
    for (int tn=0;tn<4;tn++) {
      size_t o = ((size_t)(ks*4+quad)*128 + wc*64 + tn*16 + low)*8;
      bh[tn] = *(const v8s*)(W2h + o);
      bl[tn] = *(const v8s*)(W2l + o);
    }
    #pragma unroll
    for (int tm=0;tm<4;tm++)
      #pragma unroll
      for (int tn=0;tn<4;tn++) { MFMA3(ah[tm], al[tm], bh[tn], bl[tn], acc[tm][tn]); }
  }
  __syncthreads();
  #pragma unroll
  for (int tn=0;tn<4;tn++) {
    float bv = b2[wc*64 + tn*16 + low];
    #pragma unroll
    for (int tm=0;tm<4;tm++)
      #pragma unroll
      for (int i=0;i<4;i++) {
        int idx = (wr*64+tm*16+quad*4+i)*136 + wc*64+tn*16+low;
        short2 t = f2bf2v(leakyf(acc[tm][tn][i] + bv));
        Hh[idx] = t.x; Hl[idx] = t.y;
      }
  }
  __syncthreads();

  // ---------------- layer 3 ----------------
  #pragma unroll
  for (int tm=0;tm<4;tm++)
    #pragma unroll
    for (int tn=0;tn<4;tn++) acc[tm][tn] = (f32x4)0.f;
  #pragma unroll
  for (int ks=0;ks<4;ks++) {
    v8s ah[4], al[4], bh[4], bl[4];
    #pragma unroll
    for (int tm=0;tm<4;tm++) {
      int idx = (wr*64+tm*16+low)*136 + ks*32 + quad*8;
      ah[tm] = *(const v8s*)&Hh[idx];
      al[tm] = *(const v8s*)&Hl[idx];
    }
    #pragma unroll
    for (int tn=0;tn<4;tn++) {
      size_t o = ((size_t)(ks*4+quad)*128 + wc*64 + tn*16 + low)*8;
      bh[tn] = *(const v8s*)(W3h + o);
      bl[tn] = *(const v8s*)(W3l + o);
    }
    #pragma unroll
    for (int tm=0;tm<4;tm++)
      #pragma unroll
      for (int tn=0;tn<4;tn++) { MFMA3(ah[tm], al[tm], bh[tn], bl[tn], acc[tm][tn]); }
  }
  #pragma unroll
  for (int tn=0;tn<4;tn++) {
    float bv = b3[wc*64 + tn*16 + low];
    #pragma unroll
    for (int tm=0;tm<4;tm++)
      #pragma unroll
      for (int i=0;i<4;i++) acc[tm][tn][i] += bv;
  }

  // ---------------- fused LayerNorm ----------------
  #pragma unroll
  for (int tm=0;tm<4;tm++)
    #pragma unroll
    for (int i=0;i<4;i++) {
      float s = acc[tm][0][i] + acc[tm][1][i] + acc[tm][2][i] + acc[tm][3][i];
      float q = acc[tm][0][i]*acc[tm][0][i] + acc[tm][1][i]*acc[tm][1][i]
              + acc[tm][2][i]*acc[tm][2][i] + acc[tm][3][i]*acc[tm][3][i];
      s += __shfl_xor(s, 1); q += __shfl_xor(q, 1);
      s += __shfl_xor(s, 2); q += __shfl_xor(q, 2);
      s += __shfl_xor(s, 4); q += __shfl_xor(q, 4);
      s += __shfl_xor(s, 8); q += __shfl_xor(q, 8);
      if (low == tm*4 + i) {
        int r = wr*64 + tm*16 + quad*4 + i;
        lnS[r][wc] = s; lnQ[r][wc] = q;
      }
    }
  __syncthreads();   // also guarantees all layer-3 H reads are done (Hf reuse below)

  float g4[4], bb4[4];
  #pragma unroll
  for (int tn=0;tn<4;tn++) { int c = wc*64+tn*16+low; g4[tn] = g[c]; bb4[tn] = bb[c]; }

  #pragma unroll
  for (int tm=0;tm<4;tm++)
    #pragma unroll
    for (int i=0;i<4;i++) {
      int r = wr*64 + tm*16 + quad*4 + i;
      float s = lnS[r][0] + lnS[r][1];
      float q = lnQ[r][0] + lnQ[r][1];
      float m = s * (1.f/128.f);
      float var = q * (1.f/128.f) - m*m;
      float rs = rsqrtf(var + LN_EPS);
      int gr = row0 + r;
      if (!SCATTER && gr >= nrows) continue;
      #pragma unroll
      for (int tn=0;tn<4;tn++) {
        float v = (acc[tm][tn][i] - m) * rs * g4[tn] + bb4[tn];
        int c = wc*64 + tn*16 + low;
        if (SCATTER) Hf[r*132 + c] = v;           // stage for seg-reduce
        else         out[(size_t)gr*DD + c] = v;
      }
    }

  if (SCATTER) {
    __syncthreads();
    int col  = tid & 127;
    int rbeg = (tid >> 7) * 64, rend = rbeg + 64;
    float accv = Hf[rbeg*132 + col];
    int cur = sidx_s[rbeg];
    for (int r = rbeg + 1; r < rend; r++) {
      int sv = sidx_s[r];
      float hv = Hf[r*132 + col];
      if (sv != cur) {
        atomicAdd(&out[(size_t)cur*DD + col], accv);
        accv = hv; cur = sv;
      } else accv += hv;
    }
    atomicAdd(&out[(size_t)cur*DD + col], accv);
  }
}

// ---------------------------------------------------------------------------
// outbf[r] = bf16((x[r] @ W + initv) * rowscale[r])   (64-row tiles)
// ---------------------------------------------------------------------------
__global__ __launch_bounds__(256)
void gemm_mfma_kernel(const float* __restrict__ x,
                      const short* __restrict__ Wh, const short* __restrict__ Wl,
                      const float* __restrict__ initv, const float* __restrict__ rowscale,
                      unsigned short* __restrict__ outbf, int nrows)
{
  const int tid  = threadIdx.x;
  const int lane = tid & 63, wave = tid >> 6;
  const int wr = wave >> 1, wc = wave & 1;
  const int quad = lane >> 4, low = lane & 15;
  const int row0 = blockIdx.x * 64;

  f32x4 acc[2][4];
  #pragma unroll
  for (int tm=0;tm<2;tm++)
    #pragma unroll
    for (int tn=0;tn<4;tn++) acc[tm][tn] = (f32x4)0.f;

  #pragma unroll
  for (int ks=0;ks<4;ks++) {
    v8s ah[2], al[2], bh[4], bl[4];
    #pragma unroll
    for (int tm=0;tm<2;tm++) {
      int r = row0 + wr*32 + tm*16 + low;
      v8s h = (v8s)0, l = (v8s)0;
      if (r < nrows) {
        const float* p = x + (size_t)r*DD + ks*32 + quad*8;
        float4 f0 = *(const float4*)p;
        float4 f1 = *(const float4*)(p + 4);
        SPLIT8(f0, f1, h, l);
      }
      ah[tm] = h; al[tm] = l;
    }
    #pragma unroll
    for (int tn=0;tn<4;tn++) {
      size_t o = ((size_t)(ks*4+quad)*128 + wc*64 + tn*16 + low)*8;
      bh[tn] = *(const v8s*)(Wh + o);
      bl[tn] = *(const v8s*)(Wl + o);
    }
    #pragma unroll
    for (int tm=0;tm<2;tm++)
      #pragma unroll
      for (int tn=0;tn<4;tn++) { MFMA3(ah[tm], al[tm], bh[tn], bl[tn], acc[tm][tn]); }
  }

  #pragma unroll
  for (int tm=0;tm<2;tm++)
    #pragma unroll
    for (int i=0;i<4;i++) {
      int gr = row0 + wr*32 + tm*16 + quad*4 + i;
      if (gr >= nrows) continue;
      float sc = rowscale ? rowscale[gr] : 1.f;
      #pragma unroll
      for (int tn=0;tn<4;tn++) {
        int c = wc*64 + tn*16 + low;
        float iv = initv ? initv[c] : 0.f;
        outbf[(size_t)gr*DD + c] = (unsigned short)f2bf((acc[tm][tn][i] + iv) * sc);
      }
    }
}

// ---------------------------------------------------------------------------
// Column-sliced GCN aggregation on bf16 table (slice = 32 cols = 16 uints;
// slice table 3.2 MB < 4 MB/XCD L2). One wave per (node, slice); lanes =
// 4 edge-groups x 16 uints; x2 unroll; shfl-xor cross-group reduce.
// Streaming traffic (csr, resid, out) is nontemporal to protect the slice.
// ---------------------------------------------------------------------------
__global__ __launch_bounds__(256)
void gcn_agg_kernel(const unsigned* __restrict__ hb, const int* __restrict__ rowptr,
                    const int* __restrict__ csr_src, const float* __restrict__ dis,
                    const float* __restrict__ bias,
                    const float* __restrict__ resid, float* __restrict__ out, int mode)
{
  const int wv = threadIdx.x >> 6, lane = threadIdx.x & 63;
  const int nodeblk = blockIdx.x % NBLK;
  const int slice   = blockIdx.x / NBLK;   // 0..3, slice-major dispatch
  const int i = nodeblk*4 + wv;
  if (i >= NN) return;
  const int ug = lane & 15;                // uint within slice
  const int eg = lane >> 4;                // edge subgroup 0..3
  const int u  = slice*16 + ug;            // uint col 0..63

  float ax = 0.f, ay = 0.f;
  const int beg = rowptr[i], end = rowptr[i+1];
  int j = beg + eg;
  for (; j + 4 < end; j += 8) {
    int s0 = __builtin_nontemporal_load(csr_src + j);
    int s1 = __builtin_nontemporal_load(csr_src + j + 4);
    unsigned v0 = hb[(size_t)s0*64 + u];
    unsigned v1 = hb[(size_t)s1*64 + u];
    ax += bf2f((unsigned short)(v0 & 0xffff)) + bf2f((unsigned short)(v1 & 0xffff));
    ay += bf2f((unsigned short)(v0 >> 16))    + bf2f((unsigned short)(v1 >> 16));
  }
  if (j < end) {
    int s = __builtin_nontemporal_load(csr_src + j);
    unsigned v = hb[(size_t)s*64 + u];
    ax += bf2f((unsigned short)(v & 0xffff));
    ay += bf2f((unsigned short)(v >> 16));
  }
  // combine the 4 edge groups
  ax += __shfl_xor(ax, 16); ay += __shfl_xor(ay, 16);
  ax += __shfl_xor(ax, 32); ay += __shfl_xor(ay, 32);

  if (lane < 16) {
    unsigned hv = hb[(size_t)i*64 + u];    // self
    ax += bf2f((unsigned short)(hv & 0xffff));
    ay += bf2f((unsigned short)(hv >> 16));
    float di = dis[i];
    ax = ax*di + bias[2*u];
    ay = ay*di + bias[2*u+1];
    size_t o = (size_t)i*64 + u;
    float2 r;
    if (mode == 0) { r.x = leakyf(ax); r.y = leakyf(ay); }
    else {
      double dd = __builtin_nontemporal_load((const double*)resid + o);
      float2 rs = *(float2*)&dd;
      r.x = rs.x + ax; r.y = rs.y + ay;
    }
    __builtin_nontemporal_store(*(double*)&r, (double*)out + o);
  }
}

// ---------------------------------------------------------------------------
// Graph setup
// ---------------------------------------------------------------------------
__global__ void count_kernel(const int* __restrict__ src, const int* __restrict__ dst,
                             int* __restrict__ cnt_src, int* __restrict__ deg_dst)
{
  int e = blockIdx.x*blockDim.x + threadIdx.x;
  if (e < NE) {
    atomicAdd(&cnt_src[src[e]], 1);
    atomicAdd(&deg_dst[dst[e]], 1);
  }
}

__global__ void nodeparams_kernel(const int* __restrict__ deg_dst, const int* __restrict__ cnt_src,
                                  float* __restrict__ dis, float* __restrict__ invcnt)
{
  int i = blockIdx.x*blockDim.x + threadIdx.x;
  if (i < NN) {
    dis[i] = rsqrtf((float)deg_dst[i] + 1.0f);
    invcnt[i] = 1.0f / fmaxf((float)cnt_src[i], 1.0f);
  }
}

__global__ void scan_kernel(const int* __restrict__ deg, int* __restrict__ rowptr,
                            int* __restrict__ nextp)
{
  const int T = 256;
  int tid = threadIdx.x;
  int chunk = (NN + T - 1) / T;
  int begin = tid*chunk, end = begin + chunk; if (end > NN) end = NN; if (begin > NN) begin = NN;
  int s = 0;
  for (int i = begin; i < end; i++) s += deg[i];
  __shared__ int ps[T];
  ps[tid] = s; __syncthreads();
  for (int off = 1; off < T; off <<= 1) {
    int v = 0;
    if (tid >= off) v = ps[tid - off];
    __syncthreads();
    if (tid >= off) ps[tid] += v;
    __syncthreads();
  }
  int base = (tid == 0) ? 0 : ps[tid-1];
  for (int i = begin; i < end; i++) { rowptr[i] = base; nextp[i] = base; base += deg[i]; }
  if (tid == T-1) rowptr[NN] = base;
}

__global__ void fill_kernel(const int* __restrict__ src, const int* __restrict__ dst,
                            int* __restrict__ nextp, int* __restrict__ csr_src)
{
  int e = blockIdx.x*blockDim.x + threadIdx.x;
  if (e < NE) {
    int pos = atomicAdd(&nextp[dst[e]], 1);
    csr_src[pos] = src[e];
  }
}

__global__ void fill_src_kernel(const int* __restrict__ src, int* __restrict__ nexts,
                                int* __restrict__ eperm, int* __restrict__ srcsorted)
{
  int e = blockIdx.x*blockDim.x + threadIdx.x;
  if (e < NE) {
    int s = src[e];
    int pos = atomicAdd(&nexts[s], 1);
    eperm[pos] = e;
    srcsorted[pos] = s;
  }
}

__global__ void addmean_kernel(float* __restrict__ hn, const float* __restrict__ nodesum,
                               const float* __restrict__ invcnt)
{
  int t = blockIdx.x*blockDim.x + threadIdx.x;
  if (t < NN*DD) hn[t] += nodesum[t] * invcnt[t >> 7];
}

// ---------------------------------------------------------------------------
// BatchNorm stats + parallel fold into packed hi/lo bf16 conv2 weight
// ---------------------------------------------------------------------------
__global__ __launch_bounds__(256)
void bn_stats_kernel(const float* __restrict__ y, float* __restrict__ sums)
{
  int col = threadIdx.x & 127, grp = threadIdx.x >> 7;
  float s = 0.f, ss = 0.f;
  for (int i = blockIdx.x*2 + grp; i < NN; i += gridDim.x*2) {
    float v = y[(size_t)i*DD + col];
    s += v; ss += v*v;
  }
  __shared__ float ls[256], lss[256];
  ls[threadIdx.x] = s; lss[threadIdx.x] = ss;
  __syncthreads();
  if (grp == 0) {
    atomicAdd(&sums[col],      ls[col]  + ls[col+128]);
    atomicAdd(&sums[DD + col], lss[col] + lss[col+128]);
  }
}

// grid = 16 blocks; block b handles k in [b*8, b*8+8). cvec (= sums+2*DD,
// pre-zeroed) accumulated via atomics.
__global__ __launch_bounds__(256)
void bn_fold_kernel(const float* __restrict__ sums, const float* __restrict__ g,
                    const float* __restrict__ b, const float* __restrict__ W2,
                    short* __restrict__ Wfh, short* __restrict__ Wfl,
                    float* __restrict__ cvec)
{
  __shared__ float scale_s[DD], shift_s[DD];
  int tid = threadIdx.x;
  if (tid < DD) {
    float m = sums[tid] / (float)NN;
    float var = sums[DD + tid] / (float)NN - m*m;
    float is = rsqrtf(var + LN_EPS);
    float sc = is * g[tid];
    scale_s[tid] = sc;
    shift_s[tid] = b[tid] - m * sc;
  }
  __syncthreads();
  int col = tid & 127, kh = tid >> 7;   // kh = 0..1
  float cpart = 0.f;
  #pragma unroll
  for (int kk = 0; kk < 4; kk++) {
    int k = blockIdx.x*8 + kh*4 + kk;
    float w = W2[k*DD + col];
    short2 t = f2bf2v(w * scale_s[k]);
    size_t o = ((size_t)(k >> 3)*128 + col)*8 + (k & 7);
    Wfh[o] = t.x; Wfl[o] = t.y;
    cpart += shift_s[k] * w;
  }
  atomicAdd(&cvec[col], cpart);
}

// ---------------------------------------------------------------------------
extern "C" void kernel_launch(void* const* d_in, const int* in_sizes, int n_in,
                              void* d_out, int out_size, void* d_ws, size_t ws_size,
                              hipStream_t stream)
{
  const float* node_feat = (const float*)d_in[0];
  const float* edge_feat = (const float*)d_in[1];
  const int*   edge_index = (const int*)d_in[2];
  const int* src = edge_index;
  const int* dst = edge_index + NE;

  const float* enW1 = (const float*)d_in[3];  const float* enb1 = (const float*)d_in[4];
  const float* enW2 = (const float*)d_in[5];  const float* enb2 = (const float*)d_in[6];
  const float* enW3 = (const float*)d_in[7];  const float* enb3 = (const float*)d_in[8];
  const float* enlg = (const float*)d_in[9];  const float* enlb = (const float*)d_in[10];

  const float* eeW1 = (const float*)d_in[11]; const float* eeb1 = (const float*)d_in[12];
  const float* eeW2 = (const float*)d_in[13]; const float* eeb2 = (const float*)d_in[14];
  const float* eeW3 = (const float*)d_in[15]; const float* eeb3 = (const float*)d_in[16];
  const float* eelg = (const float*)d_in[17]; const float* eelb = (const float*)d_in[18];

  const float* procW = (const float*)d_in[19];
  const float* procB = (const float*)d_in[20];
  const float* bnG   = (const float*)d_in[21];
  const float* bnB   = (const float*)d_in[22];

  const float* dW1 = (const float*)d_in[23]; const float* db1 = (const float*)d_in[24];
  const float* dW2 = (const float*)d_in[25]; const float* db2 = (const float*)d_in[26];
  const float* dW3 = (const float*)d_in[27]; const float* db3 = (const float*)d_in[28];
  const float* dlg = (const float*)d_in[29]; const float* dlb = (const float*)d_in[30];

  char* ws = (char*)d_ws;
  size_t off = 0;
  auto alloc = [&](size_t bytes) -> void* {
    void* p = ws + off;
    off = (off + bytes + 255) & ~(size_t)255;
    return p;
  };
  float* hn     = (float*)alloc((size_t)NN*DD*4);
  float* ybuf   = (float*)alloc((size_t)NN*DD*4);
  float* esum   = (float*)alloc((size_t)NN*DD*4);   // edge scatter-sum accumulator
  unsigned short* hbf = (unsigned short*)alloc((size_t)NN*DD*2);  // bf16 gather table
  float* dis    = (float*)alloc(NN*4);
  float* invcnt = (float*)alloc(NN*4);
  float* bnsums = (float*)alloc(3*DD*4);   // [sum, sumsq, cvec]
  float* cvec   = bnsums + 2*DD;
  int* deg    = (int*)alloc(NN*4);
  int* cnt    = (int*)alloc(NN*4);
  int* rowptr = (int*)alloc((NN+1)*4);
  int* nextp  = (int*)alloc(NN*4);
  int* srow   = (int*)alloc((NN+1)*4);
  int* nexts  = (int*)alloc(NN*4);
  int* csr    = (int*)alloc((size_t)NE*4);
  int* eperm  = (int*)alloc((size_t)NE*4);
  int* srcsorted = (int*)alloc((size_t)NE*4);
  auto allocW = [&](int kp) { return (short*)alloc((size_t)kp*128*2); };
  short *pN1h=allocW(32),  *pN1l=allocW(32);
  short *pN2h=allocW(128), *pN2l=allocW(128);
  short *pN3h=allocW(128), *pN3l=allocW(128);
  short *pE1h=allocW(32),  *pE1l=allocW(32);
  short *pE2h=allocW(128), *pE2l=allocW(128);
  short *pE3h=allocW(128), *pE3l=allocW(128);
  short *pD1h=allocW(128), *pD1l=allocW(128);
  short *pD2h=allocW(128), *pD2l=allocW(128);
  short *pD3h=allocW(128), *pD3l=allocW(128);
  short *pP0h[5], *pP0l[5];
  for (int s = 0; s < 5; s++) { pP0h[s]=allocW(128); pP0l[s]=allocW(128); }
  short *pWfh=allocW(128), *pWfl=allocW(128);

  (void)hipMemsetAsync(deg, 0, NN*4, stream);
  (void)hipMemsetAsync(cnt, 0, NN*4, stream);
  (void)hipMemsetAsync(esum, 0, (size_t)NN*DD*4, stream);

  // pack static weights
  const int G32 = (32*128+255)/256, G128 = (128*128+255)/256;
  pack_w_kernel<<<G32, 256, 0, stream>>>(enW1, pN1h, pN1l, 19, 32);
  pack_w_kernel<<<G128,256, 0, stream>>>(enW2, pN2h, pN2l, 128, 128);
  pack_w_kernel<<<G128,256, 0, stream>>>(enW3, pN3h, pN3l, 128, 128);
  pack_w_kernel<<<G32, 256, 0, stream>>>(eeW1, pE1h, pE1l, 4, 32);
  pack_w_kernel<<<G128,256, 0, stream>>>(eeW2, pE2h, pE2l, 128, 128);
  pack_w_kernel<<<G128,256, 0, stream>>>(eeW3, pE3h, pE3l, 128, 128);
  pack_w_kernel<<<G128,256, 0, stream>>>(dW1, pD1h, pD1l, 128, 128);
  pack_w_kernel<<<G128,256, 0, stream>>>(dW2, pD2h, pD2l, 128, 128);
  pack_w_kernel<<<G128,256, 0, stream>>>(dW3, pD3h, pD3l, 128, 128);
  for (int s = 0; s < 5; s++)
    pack_w_kernel<<<G128,256,0,stream>>>(procW + (size_t)(s*2)*DD*DD, pP0h[s], pP0l[s], 128, 128);

  // graph setup
  count_kernel<<<(NE+255)/256, 256, 0, stream>>>(src, dst, cnt, deg);
  nodeparams_kernel<<<(NN+255)/256, 256, 0, stream>>>(deg, cnt, dis, invcnt);
  scan_kernel<<<1, 256, 0, stream>>>(deg, rowptr, nextp);
  scan_kernel<<<1, 256, 0, stream>>>(cnt, srow, nexts);
  fill_kernel<<<(NE+255)/256, 256, 0, stream>>>(src, dst, nextp, csr);
  fill_src_kernel<<<(NE+255)/256, 256, 0, stream>>>(src, nexts, eperm, srcsorted);

  const int GN  = (NN + 127) / 128;  // 391
  const int GE  = NE / 128;          // 6250
  const int GG  = (NN + 63) / 64;    // 782
  const int GA  = 4 * NBLK;          // sliced agg grid

  // encoders
  mlp_mfma_kernel<19, false><<<GN, 256, 0, stream>>>(node_feat, NN,
      pN1h, pN1l, enb1, pN2h, pN2l, enb2, pN3h, pN3l, enb3, enlg, enlb, hn,
      nullptr, nullptr);
  mlp_mfma_kernel<4, true><<<GE, 256, 0, stream>>>(edge_feat, NE,
      pE1h, pE1l, eeb1, pE2h, pE2l, eeb2, pE3h, pE3l, eeb3, eelg, eelb, esum,
      srcsorted, eperm);
  addmean_kernel<<<(NN*DD+255)/256, 256, 0, stream>>>(hn, esum, invcnt);

  // processor: 5 residual (conv -> leaky -> BN -> conv) steps
  for (int s = 0; s < 5; s++) {
    const float* Wc2 = procW + (size_t)(s*2+1)*DD*DD;
    const float* b0  = procB + (size_t)(s*2+0)*DD;
    const float* b1p = procB + (size_t)(s*2+1)*DD;

    gemm_mfma_kernel<<<GG, 256, 0, stream>>>(hn, pP0h[s], pP0l[s], nullptr, dis, hbf, NN);
    gcn_agg_kernel<<<GA, 256, 0, stream>>>((const unsigned*)hbf, rowptr, csr, dis,
                                           b0, nullptr, ybuf, 0);
    (void)hipMemsetAsync(bnsums, 0, 3*DD*4, stream);
    bn_stats_kernel<<<512, 256, 0, stream>>>(ybuf, bnsums);
    bn_fold_kernel<<<16, 256, 0, stream>>>(bnsums, bnG + s*DD, bnB + s*DD, Wc2, pWfh, pWfl, cvec);
    gemm_mfma_kernel<<<GG, 256, 0, stream>>>(ybuf, pWfh, pWfl, cvec, dis, hbf, NN);
    gcn_agg_kernel<<<GA, 256, 0, stream>>>((const unsigned*)hbf, rowptr, csr, dis,
                                           b1p, hn, hn, 1);
  }

  // decoder -> d_out (fp32)
  mlp_mfma_kernel<128, false><<<GN, 256, 0, stream>>>(hn, NN,
      pD1h, pD1l, db1, pD2h, pD2l, db2, pD3h, pD3l, db3, dlg, dlb, (float*)d_out,
      nullptr, nullptr);
}

// Round 8
// 1622.610 us; speedup vs baseline: 1.5125x; 1.5125x over previous
//
#include <hip/hip_runtime.h>

#define NN 50000
#define NE 800000
#define DD 128
#define LN_EPS 1e-5f

typedef __attribute__((ext_vector_type(8))) short v8s;    // 8 bf16
typedef __attribute__((ext_vector_type(4))) float f32x4;  // MFMA acc

__device__ __forceinline__ float leakyf(float x){ return x > 0.f ? x : 0.05f*x; }
__device__ __forceinline__ short f2bf(float f){
  unsigned u = __float_as_uint(f);
  u = (u + 0x7fffu + ((u >> 16) & 1u)) >> 16;   // RNE
  return (short)u;
}
__device__ __forceinline__ float bf2f(unsigned short h){
  return __uint_as_float(((unsigned)h) << 16);
}
// split fp32 -> {hi, lo}: hi = truncated top-16 (cheap), lo = RNE(residual).
__device__ __forceinline__ short2 f2bf2v(float v){
  unsigned u = __float_as_uint(v);
  short hi = (short)(u >> 16);
  float lo = v - __uint_as_float(u & 0xffff0000u);
  return make_short2(hi, f2bf(lo));
}

// ---------------------------------------------------------------------------
// Pack fp32 W[K][128] -> two bf16 planes Wh/Wl, layout [(k>>3)*128 + n][k&7]
// ---------------------------------------------------------------------------
__global__ void pack_w_kernel(const float* __restrict__ W, short* __restrict__ Wh,
                              short* __restrict__ Wl, int K, int Kp)
{
  int idx = blockIdx.x*256 + threadIdx.x;
  if (idx >= Kp*128) return;
  int k = idx >> 7, n = idx & 127;
  float v = (k < K) ? W[k*128 + n] : 0.f;
  short2 t = f2bf2v(v);
  size_t o = ((size_t)(k >> 3)*128 + n)*8 + (k & 7);
  Wh[o] = t.x; Wl[o] = t.y;
}

// full split-split product (A has hi+lo)
#define MFMA3(ah, al, bh, bl, ac) \
  ac = __builtin_amdgcn_mfma_f32_16x16x32_bf16(al, bh, ac, 0,0,0); \
  ac = __builtin_amdgcn_mfma_f32_16x16x32_bf16(ah, bl, ac, 0,0,0); \
  ac = __builtin_amdgcn_mfma_f32_16x16x32_bf16(ah, bh, ac, 0,0,0);

// A exact-bf16 (no lo plane): 2 MFMAs
#define MFMA2(ah, bh, bl, ac) \
  ac = __builtin_amdgcn_mfma_f32_16x16x32_bf16(ah, bl, ac, 0,0,0); \
  ac = __builtin_amdgcn_mfma_f32_16x16x32_bf16(ah, bh, ac, 0,0,0);

#define SPLIT8(f0, f1, h, l) { \
  short2 t0 = f2bf2v(f0.x), t1 = f2bf2v(f0.y), t2 = f2bf2v(f0.z), t3 = f2bf2v(f0.w); \
  short2 t4 = f2bf2v(f1.x), t5 = f2bf2v(f1.y), t6 = f2bf2v(f1.z), t7 = f2bf2v(f1.w); \
  h[0]=t0.x; l[0]=t0.y; h[1]=t1.x; l[1]=t1.y; h[2]=t2.x; l[2]=t2.y; h[3]=t3.x; l[3]=t3.y; \
  h[4]=t4.x; l[4]=t4.y; h[5]=t5.x; l[5]=t5.y; h[6]=t6.x; l[6]=t6.y; h[7]=t7.x; l[7]=t7.y; }

// ---------------------------------------------------------------------------
// 3-layer MLP + LayerNorm. Layer-1 inputs and all weights hi/lo split
// (fp32-grade); hidden activations single-bf16 (layers 2/3 use 2 MFMAs).
// SCATTER (edge encoder): edges processed in src-sorted order via eperm,
// output seg-reduced per src in LDS, one atomicAdd per (segment, col).
// ---------------------------------------------------------------------------
template<int IN_W, bool SCATTER>
__global__ __launch_bounds__(256)
void mlp_mfma_kernel(const float* __restrict__ x, int nrows,
                     const short* __restrict__ W1h, const short* __restrict__ W1l,
                     const float* __restrict__ b1,
                     const short* __restrict__ W2h, const short* __restrict__ W2l,
                     const float* __restrict__ b2,
                     const short* __restrict__ W3h, const short* __restrict__ W3l,
                     const float* __restrict__ b3,
                     const float* __restrict__ g, const float* __restrict__ bb,
                     float* __restrict__ out,
                     const int* __restrict__ sidx,   // src-sorted src values
                     const int* __restrict__ eperm)  // sorted pos -> edge id
{
  constexpr int L1K = (IN_W + 31) / 32;
  // SCATTER needs a 128x132 fp32 seg buffer; it aliases the bf16 act plane.
  constexpr int HSHORTS = SCATTER ? (2*128*132) : (128*136);
  __shared__ __align__(16) short Hmem[HSHORTS];
  short* Hh = Hmem;                       // act plane, stride 136
  float* Hf = (float*)Hmem;               // seg buffer, stride 132 (SCATTER)
  __shared__ float lnS[128][2], lnQ[128][2];
  __shared__ int sidx_s[128];
  __shared__ int eperm_s[128];

  const int tid  = threadIdx.x;
  const int lane = tid & 63, wave = tid >> 6;
  const int wr = wave >> 1, wc = wave & 1;
  const int quad = lane >> 4, low = lane & 15;
  const int row0 = blockIdx.x * 128;

  if (SCATTER) {
    if (tid < 128) {
      sidx_s[tid]  = sidx[row0 + tid];   // NE % 128 == 0
      eperm_s[tid] = eperm[row0 + tid];
    }
    __syncthreads();
  }

  f32x4 acc[4][4];

  // ---------------- layer 1 (hi/lo A from global) ----------------
  #pragma unroll
  for (int tm=0;tm<4;tm++)
    #pragma unroll
    for (int tn=0;tn<4;tn++) acc[tm][tn] = (f32x4)0.f;

  for (int ks = 0; ks < L1K; ks++) {
    v8s ah[4], al[4], bh[4], bl[4];
    #pragma unroll
    for (int tm=0;tm<4;tm++) {
      int lr = wr*64 + tm*16 + low;
      v8s h = (v8s)0, l = (v8s)0;
      if (SCATTER && IN_W == 4) {
        if (quad == 0) {
          int e = eperm_s[lr];
          float4 f = ((const float4*)x)[e];
          short2 t0 = f2bf2v(f.x), t1 = f2bf2v(f.y), t2 = f2bf2v(f.z), t3 = f2bf2v(f.w);
          h[0]=t0.x; l[0]=t0.y; h[1]=t1.x; l[1]=t1.y;
          h[2]=t2.x; l[2]=t2.y; h[3]=t3.x; l[3]=t3.y;
        }
      } else if (IN_W % 32 == 0) {
        int r = row0 + lr;
        if (r < nrows) {
          const float* p = x + (size_t)r*IN_W + ks*32 + quad*8;
          float4 f0 = *(const float4*)p;
          float4 f1 = *(const float4*)(p + 4);
          SPLIT8(f0, f1, h, l);
        }
      } else {
        int r = row0 + lr;
        #pragma unroll
        for (int j=0;j<8;j++) {
          int k = ks*32 + quad*8 + j;
          if (k < IN_W && r < nrows) {
            short2 t = f2bf2v(x[(size_t)r*IN_W + k]);
            h[j] = t.x; l[j] = t.y;
          }
        }
      }
      ah[tm] = h; al[tm] = l;
    }
    #pragma unroll
    for (int tn=0;tn<4;tn++) {
      size_t o = ((size_t)(ks*4+quad)*128 + wc*64 + tn*16 + low)*8;
      bh[tn] = *(const v8s*)(W1h + o);
      bl[tn] = *(const v8s*)(W1l + o);
    }
    #pragma unroll
    for (int tm=0;tm<4;tm++)
      #pragma unroll
      for (int tn=0;tn<4;tn++) { MFMA3(ah[tm], al[tm], bh[tn], bl[tn], acc[tm][tn]); }
  }
  if (SCATTER) __syncthreads();
  #pragma unroll
  for (int tn=0;tn<4;tn++) {
    float bv = b1[wc*64 + tn*16 + low];
    #pragma unroll
    for (int tm=0;tm<4;tm++)
      #pragma unroll
      for (int i=0;i<4;i++) {
        int idx = (wr*64+tm*16+quad*4+i)*136 + wc*64+tn*16+low;
        Hh[idx] = f2bf(leakyf(acc[tm][tn][i] + bv));
      }
  }
  __syncthreads();

  // ---------------- layer 2 (bf16 A from LDS, 2 MFMAs) ----------------
  #pragma unroll
  for (int tm=0;tm<4;tm++)
    #pragma unroll
    for (int tn=0;tn<4;tn++) acc[tm][tn] = (f32x4)0.f;
  #pragma unroll
  for (int ks=0;ks<4;ks++) {
    v8s ah[4], bh[4], bl[4];
    #pragma unroll
    for (int tm=0;tm<4;tm++)
      ah[tm] = *(const v8s*)&Hh[(wr*64+tm*16+low)*136 + ks*32 + quad*8];
    #pragma unroll
    for (int tn=0;tn<4;tn++) {
      size_t o = ((size_t)(ks*4+quad)*128 + wc*64 + tn*16 + low)*8;
      bh[tn] = *(const v8s*)(W2h + o);
      bl[tn] = *(const v8s*)(W2l + o);
    }
    #pragma unroll
    for (int tm=0;tm<4;tm++)
      #pragma unroll
      for (int tn=0;tn<4;tn++) { MFMA2(ah[tm], bh[tn], bl[tn], acc[tm][tn]); }
  }
  __syncthreads();
  #pragma unroll
  for (int tn=0;tn<4;tn++) {
    float bv = b2[wc*64 + tn*16 + low];
    #pragma unroll
    for (int tm=0;tm<4;tm++)
      #pragma unroll
      for (int i=0;i<4;i++) {
        int idx = (wr*64+tm*16+quad*4+i)*136 + wc*64+tn*16+low;
        Hh[idx] = f2bf(leakyf(acc[tm][tn][i] + bv));
      }
  }
  __syncthreads();

  // ---------------- layer 3 (bf16 A from LDS, 2 MFMAs) ----------------
  #pragma unroll
  for (int tm=0;tm<4;tm++)
    #pragma unroll
    for (int tn=0;tn<4;tn++) acc[tm][tn] = (f32x4)0.f;
  #pragma unroll
  for (int ks=0;ks<4;ks++) {
    v8s ah[4], bh[4], bl[4];
    #pragma unroll
    for (int tm=0;tm<4;tm++)
      ah[tm] = *(const v8s*)&Hh[(wr*64+tm*16+low)*136 + ks*32 + quad*8];
    #pragma unroll
    for (int tn=0;tn<4;tn++) {
      size_t o = ((size_t)(ks*4+quad)*128 + wc*64 + tn*16 + low)*8;
      bh[tn] = *(const v8s*)(W3h + o);
      bl[tn] = *(const v8s*)(W3l + o);
    }
    #pragma unroll
    for (int tm=0;tm<4;tm++)
      #pragma unroll
      for (int tn=0;tn<4;tn++) { MFMA2(ah[tm], bh[tn], bl[tn], acc[tm][tn]); }
  }
  #pragma unroll
  for (int tn=0;tn<4;tn++) {
    float bv = b3[wc*64 + tn*16 + low];
    #pragma unroll
    for (int tm=0;tm<4;tm++)
      #pragma unroll
      for (int i=0;i<4;i++) acc[tm][tn][i] += bv;
  }

  // ---------------- fused LayerNorm ----------------
  #pragma unroll
  for (int tm=0;tm<4;tm++)
    #pragma unroll
    for (int i=0;i<4;i++) {
      float s = acc[tm][0][i] + acc[tm][1][i] + acc[tm][2][i] + acc[tm][3][i];
      float q = acc[tm][0][i]*acc[tm][0][i] + acc[tm][1][i]*acc[tm][1][i]
              + acc[tm][2][i]*acc[tm][2][i] + acc[tm][3][i]*acc[tm][3][i];
      s += __shfl_xor(s, 1); q += __shfl_xor(q, 1);
      s += __shfl_xor(s, 2); q += __shfl_xor(q, 2);
      s += __shfl_xor(s, 4); q += __shfl_xor(q, 4);
      s += __shfl_xor(s, 8); q += __shfl_xor(q, 8);
      if (low == tm*4 + i) {
        int r = wr*64 + tm*16 + quad*4 + i;
        lnS[r][wc] = s; lnQ[r][wc] = q;
      }
    }
  __syncthreads();   // all layer-3 H reads done (Hf aliasing below is safe)

  float g4[4], bb4[4];
  #pragma unroll
  for (int tn=0;tn<4;tn++) { int c = wc*64+tn*16+low; g4[tn] = g[c]; bb4[tn] = bb[c]; }

  #pragma unroll
  for (int tm=0;tm<4;tm++)
    #pragma unroll
    for (int i=0;i<4;i++) {
      int r = wr*64 + tm*16 + quad*4 + i;
      float s = lnS[r][0] + lnS[r][1];
      float q = lnQ[r][0] + lnQ[r][1];
      float m = s * (1.f/128.f);
      float var = q * (1.f/128.f) - m*m;
      float rs = rsqrtf(var + LN_EPS);
      int gr = row0 + r;
      if (!SCATTER && gr >= nrows) continue;
      #pragma unroll
      for (int tn=0;tn<4;tn++) {
        float v = (acc[tm][tn][i] - m) * rs * g4[tn] + bb4[tn];
        int c = wc*64 + tn*16 + low;
        if (SCATTER) Hf[r*132 + c] = v;           // stage for seg-reduce
        else         out[(size_t)gr*DD + c] = v;
      }
    }

  if (SCATTER) {
    __syncthreads();
    int col  = tid & 127;
    int rbeg = (tid >> 7) * 64, rend = rbeg + 64;
    float accv = Hf[rbeg*132 + col];
    int cur = sidx_s[rbeg];
    for (int r = rbeg + 1; r < rend; r++) {
      int sv = sidx_s[r];
      float hv = Hf[r*132 + col];
      if (sv != cur) {
        atomicAdd(&out[(size_t)cur*DD + col], accv);
        accv = hv; cur = sv;
      } else accv += hv;
    }
    atomicAdd(&out[(size_t)cur*DD + col], accv);
  }
}

// ---------------------------------------------------------------------------
// outbf[r] = bf16((x[r] @ W + initv) * rowscale[r])   (64-row tiles)
// ---------------------------------------------------------------------------
__global__ __launch_bounds__(256)
void gemm_mfma_kernel(const float* __restrict__ x,
                      const short* __restrict__ Wh, const short* __restrict__ Wl,
                      const float* __restrict__ initv, const float* __restrict__ rowscale,
                      unsigned short* __restrict__ outbf, int nrows)
{
  const int tid  = threadIdx.x;
  const int lane = tid & 63, wave = tid >> 6;
  const int wr = wave >> 1, wc = wave & 1;
  const int quad = lane >> 4, low = lane & 15;
  const int row0 = blockIdx.x * 64;

  f32x4 acc[2][4];
  #pragma unroll
  for (int tm=0;tm<2;tm++)
    #pragma unroll
    for (int tn=0;tn<4;tn++) acc[tm][tn] = (f32x4)0.f;

  #pragma unroll
  for (int ks=0;ks<4;ks++) {
    v8s ah[2], al[2], bh[4], bl[4];
    #pragma unroll
    for (int tm=0;tm<2;tm++) {
      int r = row0 + wr*32 + tm*16 + low;
      v8s h = (v8s)0, l = (v8s)0;
      if (r < nrows) {
        const float* p = x + (size_t)r*DD + ks*32 + quad*8;
        float4 f0 = *(const float4*)p;
        float4 f1 = *(const float4*)(p + 4);
        SPLIT8(f0, f1, h, l);
      }
      ah[tm] = h; al[tm] = l;
    }
    #pragma unroll
    for (int tn=0;tn<4;tn++) {
      size_t o = ((size_t)(ks*4+quad)*128 + wc*64 + tn*16 + low)*8;
      bh[tn] = *(const v8s*)(Wh + o);
      bl[tn] = *(const v8s*)(Wl + o);
    }
    #pragma unroll
    for (int tm=0;tm<2;tm++)
      #pragma unroll
      for (int tn=0;tn<4;tn++) { MFMA3(ah[tm], al[tm], bh[tn], bl[tn], acc[tm][tn]); }
  }

  #pragma unroll
  for (int tm=0;tm<2;tm++)
    #pragma unroll
    for (int i=0;i<4;i++) {
      int gr = row0 + wr*32 + tm*16 + quad*4 + i;
      if (gr >= nrows) continue;
      float sc = rowscale ? rowscale[gr] : 1.f;
      #pragma unroll
      for (int tn=0;tn<4;tn++) {
        int c = wc*64 + tn*16 + low;
        float iv = initv ? initv[c] : 0.f;
        outbf[(size_t)gr*DD + c] = (unsigned short)f2bf((acc[tm][tn][i] + iv) * sc);
      }
    }
}

// ---------------------------------------------------------------------------
// GCN aggregation on bf16-packed pre-scaled h (R6 shape: one wave per node,
// 256 B/request, unroll x8, fp32 accumulate).
// ---------------------------------------------------------------------------
__global__ __launch_bounds__(256)
void gcn_agg_kernel(const unsigned* __restrict__ hb, const int* __restrict__ rowptr,
                    const int* __restrict__ csr_src, const float* __restrict__ dis,
                    const float* __restrict__ bias,
                    const float* __restrict__ resid, float* __restrict__ out, int mode)
{
  const int wv = threadIdx.x >> 6, lane = threadIdx.x & 63;
  const int i = blockIdx.x*4 + wv;
  if (i >= NN) return;
  unsigned hv = hb[(size_t)i*64 + lane];
  float ax = bf2f((unsigned short)(hv & 0xffff)), ay = bf2f((unsigned short)(hv >> 16));
  const int beg = rowptr[i], end = rowptr[i+1];
  int j = beg;
  for (; j + 8 <= end; j += 8) {
    unsigned v0 = hb[(size_t)csr_src[j+0]*64 + lane];
    unsigned v1 = hb[(size_t)csr_src[j+1]*64 + lane];
    unsigned v2 = hb[(size_t)csr_src[j+2]*64 + lane];
    unsigned v3 = hb[(size_t)csr_src[j+3]*64 + lane];
    unsigned v4 = hb[(size_t)csr_src[j+4]*64 + lane];
    unsigned v5 = hb[(size_t)csr_src[j+5]*64 + lane];
    unsigned v6 = hb[(size_t)csr_src[j+6]*64 + lane];
    unsigned v7 = hb[(size_t)csr_src[j+7]*64 + lane];
    ax += ((bf2f((unsigned short)(v0 & 0xffff)) + bf2f((unsigned short)(v1 & 0xffff)))
         + (bf2f((unsigned short)(v2 & 0xffff)) + bf2f((unsigned short)(v3 & 0xffff))))
        + ((bf2f((unsigned short)(v4 & 0xffff)) + bf2f((unsigned short)(v5 & 0xffff)))
         + (bf2f((unsigned short)(v6 & 0xffff)) + bf2f((unsigned short)(v7 & 0xffff))));
    ay += ((bf2f((unsigned short)(v0 >> 16)) + bf2f((unsigned short)(v1 >> 16)))
         + (bf2f((unsigned short)(v2 >> 16)) + bf2f((unsigned short)(v3 >> 16))))
        + ((bf2f((unsigned short)(v4 >> 16)) + bf2f((unsigned short)(v5 >> 16)))
         + (bf2f((unsigned short)(v6 >> 16)) + bf2f((unsigned short)(v7 >> 16))));
  }
  for (; j < end; j++) {
    unsigned v = hb[(size_t)csr_src[j]*64 + lane];
    ax += bf2f((unsigned short)(v & 0xffff));
    ay += bf2f((unsigned short)(v >> 16));
  }
  float di = dis[i];
  ax = ax*di + bias[2*lane]; ay = ay*di + bias[2*lane+1];
  size_t o = (size_t)i*64 + lane;
  float2 r;
  if (mode == 0) { r.x = leakyf(ax); r.y = leakyf(ay); }
  else { float2 rs = ((const float2*)resid)[o]; r.x = rs.x + ax; r.y = rs.y + ay; }
  ((float2*)out)[o] = r;
}

// ---------------------------------------------------------------------------
// Graph setup
// ---------------------------------------------------------------------------
__global__ void count_kernel(const int* __restrict__ src, const int* __restrict__ dst,
                             int* __restrict__ cnt_src, int* __restrict__ deg_dst)
{
  int e = blockIdx.x*blockDim.x + threadIdx.x;
  if (e < NE) {
    atomicAdd(&cnt_src[src[e]], 1);
    atomicAdd(&deg_dst[dst[e]], 1);
  }
}

__global__ void nodeparams_kernel(const int* __restrict__ deg_dst, const int* __restrict__ cnt_src,
                                  float* __restrict__ dis, float* __restrict__ invcnt)
{
  int i = blockIdx.x*blockDim.x + threadIdx.x;
  if (i < NN) {
    dis[i] = rsqrtf((float)deg_dst[i] + 1.0f);
    invcnt[i] = 1.0f / fmaxf((float)cnt_src[i], 1.0f);
  }
}

__global__ void scan_kernel(const int* __restrict__ deg, int* __restrict__ rowptr,
                            int* __restrict__ nextp)
{
  const int T = 256;
  int tid = threadIdx.x;
  int chunk = (NN + T - 1) / T;
  int begin = tid*chunk, end = begin + chunk; if (end > NN) end = NN; if (begin > NN) begin = NN;
  int s = 0;
  for (int i = begin; i < end; i++) s += deg[i];
  __shared__ int ps[T];
  ps[tid] = s; __syncthreads();
  for (int off = 1; off < T; off <<= 1) {
    int v = 0;
    if (tid >= off) v = ps[tid - off];
    __syncthreads();
    if (tid >= off) ps[tid] += v;
    __syncthreads();
  }
  int base = (tid == 0) ? 0 : ps[tid-1];
  for (int i = begin; i < end; i++) { rowptr[i] = base; nextp[i] = base; base += deg[i]; }
  if (tid == T-1) rowptr[NN] = base;
}

__global__ void fill_kernel(const int* __restrict__ src, const int* __restrict__ dst,
                            int* __restrict__ nextp, int* __restrict__ csr_src)
{
  int e = blockIdx.x*blockDim.x + threadIdx.x;
  if (e < NE) {
    int pos = atomicAdd(&nextp[dst[e]], 1);
    csr_src[pos] = src[e];
  }
}

__global__ void fill_src_kernel(const int* __restrict__ src, int* __restrict__ nexts,
                                int* __restrict__ eperm, int* __restrict__ srcsorted)
{
  int e = blockIdx.x*blockDim.x + threadIdx.x;
  if (e < NE) {
    int s = src[e];
    int pos = atomicAdd(&nexts[s], 1);
    eperm[pos] = e;
    srcsorted[pos] = s;
  }
}

__global__ void addmean_kernel(float* __restrict__ hn, const float* __restrict__ nodesum,
                               const float* __restrict__ invcnt)
{
  int t = blockIdx.x*blockDim.x + threadIdx.x;
  if (t < NN*DD) hn[t] += nodesum[t] * invcnt[t >> 7];
}

// ---------------------------------------------------------------------------
// BatchNorm stats + parallel fold into packed hi/lo bf16 conv2 weight
// ---------------------------------------------------------------------------
__global__ __launch_bounds__(256)
void bn_stats_kernel(const float* __restrict__ y, float* __restrict__ sums)
{
  int col = threadIdx.x & 127, grp = threadIdx.x >> 7;
  float s = 0.f, ss = 0.f;
  for (int i = blockIdx.x*2 + grp; i < NN; i += gridDim.x*2) {
    float v = y[(size_t)i*DD + col];
    s += v; ss += v*v;
  }
  __shared__ float ls[256], lss[256];
  ls[threadIdx.x] = s; lss[threadIdx.x] = ss;
  __syncthreads();
  if (grp == 0) {
    atomicAdd(&sums[col],      ls[col]  + ls[col+128]);
    atomicAdd(&sums[DD + col], lss[col] + lss[col+128]);
  }
}

// grid = 16 blocks; block b handles k in [b*8, b*8+8). cvec pre-zeroed.
__global__ __launch_bounds__(256)
void bn_fold_kernel(const float* __restrict__ sums, const float* __restrict__ g,
                    const float* __restrict__ b, const float* __restrict__ W2,
                    short* __restrict__ Wfh, short* __restrict__ Wfl,
                    float* __restrict__ cvec)
{
  __shared__ float scale_s[DD], shift_s[DD];
  int tid = threadIdx.x;
  if (tid < DD) {
    float m = sums[tid] / (float)NN;
    float var = sums[DD + tid] / (float)NN - m*m;
    float is = rsqrtf(var + LN_EPS);
    float sc = is * g[tid];
    scale_s[tid] = sc;
    shift_s[tid] = b[tid] - m * sc;
  }
  __syncthreads();
  int col = tid & 127, kh = tid >> 7;   // kh = 0..1
  float cpart = 0.f;
  #pragma unroll
  for (int kk = 0; kk < 4; kk++) {
    int k = blockIdx.x*8 + kh*4 + kk;
    float w = W2[k*DD + col];
    short2 t = f2bf2v(w * scale_s[k]);
    size_t o = ((size_t)(k >> 3)*128 + col)*8 + (k & 7);
    Wfh[o] = t.x; Wfl[o] = t.y;
    cpart += shift_s[k] * w;
  }
  atomicAdd(&cvec[col], cpart);
}

// ---------------------------------------------------------------------------
extern "C" void kernel_launch(void* const* d_in, const int* in_sizes, int n_in,
                              void* d_out, int out_size, void* d_ws, size_t ws_size,
                              hipStream_t stream)
{
  const float* node_feat = (const float*)d_in[0];
  const float* edge_feat = (const float*)d_in[1];
  const int*   edge_index = (const int*)d_in[2];
  const int* src = edge_index;
  const int* dst = edge_index + NE;

  const float* enW1 = (const float*)d_in[3];  const float* enb1 = (const float*)d_in[4];
  const float* enW2 = (const float*)d_in[5];  const float* enb2 = (const float*)d_in[6];
  const float* enW3 = (const float*)d_in[7];  const float* enb3 = (const float*)d_in[8];
  const float* enlg = (const float*)d_in[9];  const float* enlb = (const float*)d_in[10];

  const float* eeW1 = (const float*)d_in[11]; const float* eeb1 = (const float*)d_in[12];
  const float* eeW2 = (const float*)d_in[13]; const float* eeb2 = (const float*)d_in[14];
  const float* eeW3 = (const float*)d_in[15]; const float* eeb3 = (const float*)d_in[16];
  const float* eelg = (const float*)d_in[17]; const float* eelb = (const float*)d_in[18];

  const float* procW = (const float*)d_in[19];
  const float* procB = (const float*)d_in[20];
  const float* bnG   = (const float*)d_in[21];
  const float* bnB   = (const float*)d_in[22];

  const float* dW1 = (const float*)d_in[23]; const float* db1 = (const float*)d_in[24];
  const float* dW2 = (const float*)d_in[25]; const float* db2 = (const float*)d_in[26];
  const float* dW3 = (const float*)d_in[27]; const float* db3 = (const float*)d_in[28];
  const float* dlg = (const float*)d_in[29]; const float* dlb = (const float*)d_in[30];

  char* ws = (char*)d_ws;
  size_t off = 0;
  auto alloc = [&](size_t bytes) -> void* {
    void* p = ws + off;
    off = (off + bytes + 255) & ~(size_t)255;
    return p;
  };
  float* hn     = (float*)alloc((size_t)NN*DD*4);
  float* ybuf   = (float*)alloc((size_t)NN*DD*4);
  float* esum   = (float*)alloc((size_t)NN*DD*4);   // edge scatter-sum accumulator
  unsigned short* hbf = (unsigned short*)alloc((size_t)NN*DD*2);  // bf16 gather table
  float* dis    = (float*)alloc(NN*4);
  float* invcnt = (float*)alloc(NN*4);
  float* bnsums = (float*)alloc(3*DD*4);   // [sum, sumsq, cvec]
  float* cvec   = bnsums + 2*DD;
  int* deg    = (int*)alloc(NN*4);
  int* cnt    = (int*)alloc(NN*4);
  int* rowptr = (int*)alloc((NN+1)*4);
  int* nextp  = (int*)alloc(NN*4);
  int* srow   = (int*)alloc((NN+1)*4);
  int* nexts  = (int*)alloc(NN*4);
  int* csr    = (int*)alloc((size_t)NE*4);
  int* eperm  = (int*)alloc((size_t)NE*4);
  int* srcsorted = (int*)alloc((size_t)NE*4);
  auto allocW = [&](int kp) { return (short*)alloc((size_t)kp*128*2); };
  short *pN1h=allocW(32),  *pN1l=allocW(32);
  short *pN2h=allocW(128), *pN2l=allocW(128);
  short *pN3h=allocW(128), *pN3l=allocW(128);
  short *pE1h=allocW(32),  *pE1l=allocW(32);
  short *pE2h=allocW(128), *pE2l=allocW(128);
  short *pE3h=allocW(128), *pE3l=allocW(128);
  short *pD1h=allocW(128), *pD1l=allocW(128);
  short *pD2h=allocW(128), *pD2l=allocW(128);
  short *pD3h=allocW(128), *pD3l=allocW(128);
  short *pP0h[5], *pP0l[5];
  for (int s = 0; s < 5; s++) { pP0h[s]=allocW(128); pP0l[s]=allocW(128); }
  short *pWfh=allocW(128), *pWfl=allocW(128);

  (void)hipMemsetAsync(deg, 0, NN*4, stream);
  (void)hipMemsetAsync(cnt, 0, NN*4, stream);
  (void)hipMemsetAsync(esum, 0, (size_t)NN*DD*4, stream);

  // pack static weights
  const int G32 = (32*128+255)/256, G128 = (128*128+255)/256;
  pack_w_kernel<<<G32, 256, 0, stream>>>(enW1, pN1h, pN1l, 19, 32);
  pack_w_kernel<<<G128,256, 0, stream>>>(enW2, pN2h, pN2l, 128, 128);
  pack_w_kernel<<<G128,256, 0, stream>>>(enW3, pN3h, pN3l, 128, 128);
  pack_w_kernel<<<G32, 256, 0, stream>>>(eeW1, pE1h, pE1l, 4, 32);
  pack_w_kernel<<<G128,256, 0, stream>>>(eeW2, pE2h, pE2l, 128, 128);
  pack_w_kernel<<<G128,256, 0, stream>>>(eeW3, pE3h, pE3l, 128, 128);
  pack_w_kernel<<<G128,256, 0, stream>>>(dW1, pD1h, pD1l, 128, 128);
  pack_w_kernel<<<G128,256, 0, stream>>>(dW2, pD2h, pD2l, 128, 128);
  pack_w_kernel<<<G128,256, 0, stream>>>(dW3, pD3h, pD3l, 128, 128);
  for (int s = 0; s < 5; s++)
    pack_w_kernel<<<G128,256,0,stream>>>(procW + (size_t)(s*2)*DD*DD, pP0h[s], pP0l[s], 128, 128);

  // graph setup
  count_kernel<<<(NE+255)/256, 256, 0, stream>>>(src, dst, cnt, deg);
  nodeparams_kernel<<<(NN+255)/256, 256, 0, stream>>>(deg, cnt, dis, invcnt);
  scan_kernel<<<1, 256, 0, stream>>>(deg, rowptr, nextp);
  scan_kernel<<<1, 256, 0, stream>>>(cnt, srow, nexts);
  fill_kernel<<<(NE+255)/256, 256, 0, stream>>>(src, dst, nextp, csr);
  fill_src_kernel<<<(NE+255)/256, 256, 0, stream>>>(src, nexts, eperm, srcsorted);

  const int GN  = (NN + 127) / 128;  // 391
  const int GE  = NE / 128;          // 6250
  const int GG  = (NN + 63) / 64;    // 782
  const int GA  = (NN + 3) / 4;      // 12500

  // encoders
  mlp_mfma_kernel<19, false><<<GN, 256, 0, stream>>>(node_feat, NN,
      pN1h, pN1l, enb1, pN2h, pN2l, enb2, pN3h, pN3l, enb3, enlg, enlb, hn,
      nullptr, nullptr);
  mlp_mfma_kernel<4, true><<<GE, 256, 0, stream>>>(edge_feat, NE,
      pE1h, pE1l, eeb1, pE2h, pE2l, eeb2, pE3h, pE3l, eeb3, eelg, eelb, esum,
      srcsorted, eperm);
  addmean_kernel<<<(NN*DD+255)/256, 256, 0, stream>>>(hn, esum, invcnt);

  // processor: 5 residual (conv -> leaky -> BN -> conv) steps
  for (int s = 0; s < 5; s++) {
    const float* Wc2 = procW + (size_t)(s*2+1)*DD*DD;
    const float* b0  = procB + (size_t)(s*2+0)*DD;
    const float* b1p = procB + (size_t)(s*2+1)*DD;

    gemm_mfma_kernel<<<GG, 256, 0, stream>>>(hn, pP0h[s], pP0l[s], nullptr, dis, hbf, NN);
    gcn_agg_kernel<<<GA, 256, 0, stream>>>((const unsigned*)hbf, rowptr, csr, dis,
                                           b0, nullptr, ybuf, 0);
    (void)hipMemsetAsync(bnsums, 0, 3*DD*4, stream);
    bn_stats_kernel<<<512, 256, 0, stream>>>(ybuf, bnsums);
    bn_fold_kernel<<<16, 256, 0, stream>>>(bnsums, bnG + s*DD, bnB + s*DD, Wc2, pWfh, pWfl, cvec);
    gemm_mfma_kernel<<<GG, 256, 0, stream>>>(ybuf, pWfh, pWfl, cvec, dis, hbf, NN);
    gcn_agg_kernel<<<GA, 256, 0, stream>>>((const unsigned*)hbf, rowptr, csr, dis,
                                           b1p, hn, hn, 1);
  }

  // decoder -> d_out (fp32)
  mlp_mfma_kernel<128, false><<<GN, 256, 0, stream>>>(hn, NN,
      pD1h, pD1l, db1, pD2h, pD2l, db2, pD3h, pD3l, db3, dlg, dlb, (float*)d_out,
      nullptr, nullptr);
}

// Round 9
// 1562.031 us; speedup vs baseline: 1.5712x; 1.0388x over previous
//
#include <hip/hip_runtime.h>

#define NN 50000
#define NE 800000
#define DD 128
#define LN_EPS 1e-5f

typedef __attribute__((ext_vector_type(8))) short v8s;    // 8 bf16
typedef __attribute__((ext_vector_type(4))) float f32x4;  // MFMA acc

__device__ __forceinline__ float leakyf(float x){ return x > 0.f ? x : 0.05f*x; }
__device__ __forceinline__ short f2bf(float f){
  unsigned u = __float_as_uint(f);
  u = (u + 0x7fffu + ((u >> 16) & 1u)) >> 16;   // RNE
  return (short)u;
}
__device__ __forceinline__ float bf2f(unsigned short h){
  return __uint_as_float(((unsigned)h) << 16);
}
// split fp32 -> {hi, lo}: hi = truncated top-16 (cheap), lo = RNE(residual).
__device__ __forceinline__ short2 f2bf2v(float v){
  unsigned u = __float_as_uint(v);
  short hi = (short)(u >> 16);
  float lo = v - __uint_as_float(u & 0xffff0000u);
  return make_short2(hi, f2bf(lo));
}

// ---------------------------------------------------------------------------
// Pack fp32 W[K][128] -> two bf16 planes Wh/Wl, layout [(k>>3)*128 + n][k&7]
// ---------------------------------------------------------------------------
__global__ void pack_w_kernel(const float* __restrict__ W, short* __restrict__ Wh,
                              short* __restrict__ Wl, int K, int Kp)
{
  int idx = blockIdx.x*256 + threadIdx.x;
  if (idx >= Kp*128) return;
  int k = idx >> 7, n = idx & 127;
  float v = (k < K) ? W[k*128 + n] : 0.f;
  short2 t = f2bf2v(v);
  size_t o = ((size_t)(k >> 3)*128 + n)*8 + (k & 7);
  Wh[o] = t.x; Wl[o] = t.y;
}

// full split-split product (A has hi+lo)
#define MFMA3(ah, al, bh, bl, ac) \
  ac = __builtin_amdgcn_mfma_f32_16x16x32_bf16(al, bh, ac, 0,0,0); \
  ac = __builtin_amdgcn_mfma_f32_16x16x32_bf16(ah, bl, ac, 0,0,0); \
  ac = __builtin_amdgcn_mfma_f32_16x16x32_bf16(ah, bh, ac, 0,0,0);

// A exact-bf16 (no lo plane): 2 MFMAs
#define MFMA2(ah, bh, bl, ac) \
  ac = __builtin_amdgcn_mfma_f32_16x16x32_bf16(ah, bl, ac, 0,0,0); \
  ac = __builtin_amdgcn_mfma_f32_16x16x32_bf16(ah, bh, ac, 0,0,0);

#define SPLIT8(f0, f1, h, l) { \
  short2 t0 = f2bf2v(f0.x), t1 = f2bf2v(f0.y), t2 = f2bf2v(f0.z), t3 = f2bf2v(f0.w); \
  short2 t4 = f2bf2v(f1.x), t5 = f2bf2v(f1.y), t6 = f2bf2v(f1.z), t7 = f2bf2v(f1.w); \
  h[0]=t0.x; l[0]=t0.y; h[1]=t1.x; l[1]=t1.y; h[2]=t2.x; l[2]=t2.y; h[3]=t3.x; l[3]=t3.y; \
  h[4]=t4.x; l[4]=t4.y; h[5]=t5.x; l[5]=t5.y; h[6]=t6.x; l[6]=t6.y; h[7]=t7.x; l[7]=t7.y; }

// ---------------------------------------------------------------------------
// 3-layer MLP + LayerNorm. Layer-1 inputs and all weights hi/lo split;
// hidden activations single-bf16 (layers 2/3 use 2 MFMAs).
// SCATTER: seg-reduce staging in bf16, aliasing the act plane (LDS ~38 KB
// -> 4 blocks/CU for latency hiding of the eperm gather).
// ---------------------------------------------------------------------------
template<int IN_W, bool SCATTER>
__global__ __launch_bounds__(256)
void mlp_mfma_kernel(const float* __restrict__ x, int nrows,
                     const short* __restrict__ W1h, const short* __restrict__ W1l,
                     const float* __restrict__ b1,
                     const short* __restrict__ W2h, const short* __restrict__ W2l,
                     const float* __restrict__ b2,
                     const short* __restrict__ W3h, const short* __restrict__ W3l,
                     const float* __restrict__ b3,
                     const float* __restrict__ g, const float* __restrict__ bb,
                     float* __restrict__ out,
                     const int* __restrict__ sidx,   // src-sorted src values
                     const int* __restrict__ eperm)  // sorted pos -> edge id
{
  constexpr int L1K = (IN_W + 31) / 32;
  __shared__ __align__(16) short Hh[128*136];   // act plane; reused (stride 132) as bf16 seg buffer
  __shared__ float lnS[128][2], lnQ[128][2];
  __shared__ int sidx_s[128];
  __shared__ int eperm_s[128];

  const int tid  = threadIdx.x;
  const int lane = tid & 63, wave = tid >> 6;
  const int wr = wave >> 1, wc = wave & 1;
  const int quad = lane >> 4, low = lane & 15;
  const int row0 = blockIdx.x * 128;

  if (SCATTER) {
    if (tid < 128) {
      sidx_s[tid]  = sidx[row0 + tid];   // NE % 128 == 0
      eperm_s[tid] = eperm[row0 + tid];
    }
    __syncthreads();
  }

  f32x4 acc[4][4];

  // ---------------- layer 1 (hi/lo A from global) ----------------
  #pragma unroll
  for (int tm=0;tm<4;tm++)
    #pragma unroll
    for (int tn=0;tn<4;tn++) acc[tm][tn] = (f32x4)0.f;

  for (int ks = 0; ks < L1K; ks++) {
    v8s ah[4], al[4], bh[4], bl[4];
    #pragma unroll
    for (int tm=0;tm<4;tm++) {
      int lr = wr*64 + tm*16 + low;
      v8s h = (v8s)0, l = (v8s)0;
      if (SCATTER && IN_W == 4) {
        if (quad == 0) {
          int e = eperm_s[lr];
          float4 f = ((const float4*)x)[e];
          short2 t0 = f2bf2v(f.x), t1 = f2bf2v(f.y), t2 = f2bf2v(f.z), t3 = f2bf2v(f.w);
          h[0]=t0.x; l[0]=t0.y; h[1]=t1.x; l[1]=t1.y;
          h[2]=t2.x; l[2]=t2.y; h[3]=t3.x; l[3]=t3.y;
        }
      } else if (IN_W % 32 == 0) {
        int r = row0 + lr;
        if (r < nrows) {
          const float* p = x + (size_t)r*IN_W + ks*32 + quad*8;
          float4 f0 = *(const float4*)p;
          float4 f1 = *(const float4*)(p + 4);
          SPLIT8(f0, f1, h, l);
        }
      } else {
        int r = row0 + lr;
        #pragma unroll
        for (int j=0;j<8;j++) {
          int k = ks*32 + quad*8 + j;
          if (k < IN_W && r < nrows) {
            short2 t = f2bf2v(x[(size_t)r*IN_W + k]);
            h[j] = t.x; l[j] = t.y;
          }
        }
      }
      ah[tm] = h; al[tm] = l;
    }
    #pragma unroll
    for (int tn=0;tn<4;tn++) {
      size_t o = ((size_t)(ks*4+quad)*128 + wc*64 + tn*16 + low)*8;
      bh[tn] = *(const v8s*)(W1h + o);
      bl[tn] = *(const v8s*)(W1l + o);
    }
    #pragma unroll
    for (int tm=0;tm<4;tm++)
      #pragma unroll
      for (int tn=0;tn<4;tn++) { MFMA3(ah[tm], al[tm], bh[tn], bl[tn], acc[tm][tn]); }
  }
  if (SCATTER) __syncthreads();
  #pragma unroll
  for (int tn=0;tn<4;tn++) {
    float bv = b1[wc*64 + tn*16 + low];
    #pragma unroll
    for (int tm=0;tm<4;tm++)
      #pragma unroll
      for (int i=0;i<4;i++) {
        int idx = (wr*64+tm*16+quad*4+i)*136 + wc*64+tn*16+low;
        Hh[idx] = f2bf(leakyf(acc[tm][tn][i] + bv));
      }
  }
  __syncthreads();

  // ---------------- layer 2 (bf16 A from LDS, 2 MFMAs) ----------------
  #pragma unroll
  for (int tm=0;tm<4;tm++)
    #pragma unroll
    for (int tn=0;tn<4;tn++) acc[tm][tn] = (f32x4)0.f;
  #pragma unroll
  for (int ks=0;ks<4;ks++) {
    v8s ah[4], bh[4], bl[4];
    #pragma unroll
    for (int tm=0;tm<4;tm++)
      ah[tm] = *(const v8s*)&Hh[(wr*64+tm*16+low)*136 + ks*32 + quad*8];
    #pragma unroll
    for (int tn=0;tn<4;tn++) {
      size_t o = ((size_t)(ks*4+quad)*128 + wc*64 + tn*16 + low)*8;
      bh[tn] = *(const v8s*)(W2h + o);
      bl[tn] = *(const v8s*)(W2l + o);
    }
    #pragma unroll
    for (int tm=0;tm<4;tm++)
      #pragma unroll
      for (int tn=0;tn<4;tn++) { MFMA2(ah[tm], bh[tn], bl[tn], acc[tm][tn]); }
  }
  __syncthreads();
  #pragma unroll
  for (int tn=0;tn<4;tn++) {
    float bv = b2[wc*64 + tn*16 + low];
    #pragma unroll
    for (int tm=0;tm<4;tm++)
      #pragma unroll
      for (int i=0;i<4;i++) {
        int idx = (wr*64+tm*16+quad*4+i)*136 + wc*64+tn*16+low;
        Hh[idx] = f2bf(leakyf(acc[tm][tn][i] + bv));
      }
  }
  __syncthreads();

  // ---------------- layer 3 (bf16 A from LDS, 2 MFMAs) ----------------
  #pragma unroll
  for (int tm=0;tm<4;tm++)
    #pragma unroll
    for (int tn=0;tn<4;tn++) acc[tm][tn] = (f32x4)0.f;
  #pragma unroll
  for (int ks=0;ks<4;ks++) {
    v8s ah[4], bh[4], bl[4];
    #pragma unroll
    for (int tm=0;tm<4;tm++)
      ah[tm] = *(const v8s*)&Hh[(wr*64+tm*16+low)*136 + ks*32 + quad*8];
    #pragma unroll
    for (int tn=0;tn<4;tn++) {
      size_t o = ((size_t)(ks*4+quad)*128 + wc*64 + tn*16 + low)*8;
      bh[tn] = *(const v8s*)(W3h + o);
      bl[tn] = *(const v8s*)(W3l + o);
    }
    #pragma unroll
    for (int tm=0;tm<4;tm++)
      #pragma unroll
      for (int tn=0;tn<4;tn++) { MFMA2(ah[tm], bh[tn], bl[tn], acc[tm][tn]); }
  }
  #pragma unroll
  for (int tn=0;tn<4;tn++) {
    float bv = b3[wc*64 + tn*16 + low];
    #pragma unroll
    for (int tm=0;tm<4;tm++)
      #pragma unroll
      for (int i=0;i<4;i++) acc[tm][tn][i] += bv;
  }

  // ---------------- fused LayerNorm ----------------
  #pragma unroll
  for (int tm=0;tm<4;tm++)
    #pragma unroll
    for (int i=0;i<4;i++) {
      float s = acc[tm][0][i] + acc[tm][1][i] + acc[tm][2][i] + acc[tm][3][i];
      float q = acc[tm][0][i]*acc[tm][0][i] + acc[tm][1][i]*acc[tm][1][i]
              + acc[tm][2][i]*acc[tm][2][i] + acc[tm][3][i]*acc[tm][3][i];
      s += __shfl_xor(s, 1); q += __shfl_xor(q, 1);
      s += __shfl_xor(s, 2); q += __shfl_xor(q, 2);
      s += __shfl_xor(s, 4); q += __shfl_xor(q, 4);
      s += __shfl_xor(s, 8); q += __shfl_xor(q, 8);
      if (low == tm*4 + i) {
        int r = wr*64 + tm*16 + quad*4 + i;
        lnS[r][wc] = s; lnQ[r][wc] = q;
      }
    }
  __syncthreads();   // all layer-3 H reads done (act-plane reuse below is safe)

  float g4[4], bb4[4];
  #pragma unroll
  for (int tn=0;tn<4;tn++) { int c = wc*64+tn*16+low; g4[tn] = g[c]; bb4[tn] = bb[c]; }

  #pragma unroll
  for (int tm=0;tm<4;tm++)
    #pragma unroll
    for (int i=0;i<4;i++) {
      int r = wr*64 + tm*16 + quad*4 + i;
      float s = lnS[r][0] + lnS[r][1];
      float q = lnQ[r][0] + lnQ[r][1];
      float m = s * (1.f/128.f);
      float var = q * (1.f/128.f) - m*m;
      float rs = rsqrtf(var + LN_EPS);
      int gr = row0 + r;
      if (!SCATTER && gr >= nrows) continue;
      #pragma unroll
      for (int tn=0;tn<4;tn++) {
        float v = (acc[tm][tn][i] - m) * rs * g4[tn] + bb4[tn];
        int c = wc*64 + tn*16 + low;
        if (SCATTER) Hh[r*132 + c] = f2bf(v);     // bf16 stage for seg-reduce
        else         out[(size_t)gr*DD + c] = v;
      }
    }

  if (SCATTER) {
    __syncthreads();
    int col  = tid & 127;
    int rbeg = (tid >> 7) * 64, rend = rbeg + 64;
    float accv = bf2f((unsigned short)Hh[rbeg*132 + col]);
    int cur = sidx_s[rbeg];
    for (int r = rbeg + 1; r < rend; r++) {
      int sv = sidx_s[r];
      float hv = bf2f((unsigned short)Hh[r*132 + col]);
      if (sv != cur) {
        atomicAdd(&out[(size_t)cur*DD + col], accv);
        accv = hv; cur = sv;
      } else accv += hv;
    }
    atomicAdd(&out[(size_t)cur*DD + col], accv);
  }
}

// ---------------------------------------------------------------------------
// outbf[r] = bf16((x[r] @ W + initv) * rowscale[r])  — fp32 input (split, 3 MFMA)
// ---------------------------------------------------------------------------
__global__ __launch_bounds__(256)
void gemm_mfma_kernel(const float* __restrict__ x,
                      const short* __restrict__ Wh, const short* __restrict__ Wl,
                      const float* __restrict__ initv, const float* __restrict__ rowscale,
                      unsigned short* __restrict__ outbf, int nrows)
{
  const int tid  = threadIdx.x;
  const int lane = tid & 63, wave = tid >> 6;
  const int wr = wave >> 1, wc = wave & 1;
  const int quad = lane >> 4, low = lane & 15;
  const int row0 = blockIdx.x * 64;

  f32x4 acc[2][4];
  #pragma unroll
  for (int tm=0;tm<2;tm++)
    #pragma unroll
    for (int tn=0;tn<4;tn++) acc[tm][tn] = (f32x4)0.f;

  #pragma unroll
  for (int ks=0;ks<4;ks++) {
    v8s ah[2], al[2], bh[4], bl[4];
    #pragma unroll
    for (int tm=0;tm<2;tm++) {
      int r = row0 + wr*32 + tm*16 + low;
      v8s h = (v8s)0, l = (v8s)0;
      if (r < nrows) {
        const float* p = x + (size_t)r*DD + ks*32 + quad*8;
        float4 f0 = *(const float4*)p;
        float4 f1 = *(const float4*)(p + 4);
        SPLIT8(f0, f1, h, l);
      }
      ah[tm] = h; al[tm] = l;
    }
    #pragma unroll
    for (int tn=0;tn<4;tn++) {
      size_t o = ((size_t)(ks*4+quad)*128 + wc*64 + tn*16 + low)*8;
      bh[tn] = *(const v8s*)(Wh + o);
      bl[tn] = *(const v8s*)(Wl + o);
    }
    #pragma unroll
    for (int tm=0;tm<2;tm++)
      #pragma unroll
      for (int tn=0;tn<4;tn++) { MFMA3(ah[tm], al[tm], bh[tn], bl[tn], acc[tm][tn]); }
  }

  #pragma unroll
  for (int tm=0;tm<2;tm++)
    #pragma unroll
    for (int i=0;i<4;i++) {
      int gr = row0 + wr*32 + tm*16 + quad*4 + i;
      if (gr >= nrows) continue;
      float sc = rowscale ? rowscale[gr] : 1.f;
      #pragma unroll
      for (int tn=0;tn<4;tn++) {
        int c = wc*64 + tn*16 + low;
        float iv = initv ? initv[c] : 0.f;
        outbf[(size_t)gr*DD + c] = (unsigned short)f2bf((acc[tm][tn][i] + iv) * sc);
      }
    }
}

// ---------------------------------------------------------------------------
// Same but bf16 input (exact, 2 MFMA, 16 B/lane A-loads) — conv2 on y.
// ---------------------------------------------------------------------------
__global__ __launch_bounds__(256)
void gemm_bf_mfma_kernel(const unsigned short* __restrict__ xb,
                         const short* __restrict__ Wh, const short* __restrict__ Wl,
                         const float* __restrict__ initv, const float* __restrict__ rowscale,
                         unsigned short* __restrict__ outbf, int nrows)
{
  const int tid  = threadIdx.x;
  const int lane = tid & 63, wave = tid >> 6;
  const int wr = wave >> 1, wc = wave & 1;
  const int quad = lane >> 4, low = lane & 15;
  const int row0 = blockIdx.x * 64;

  f32x4 acc[2][4];
  #pragma unroll
  for (int tm=0;tm<2;tm++)
    #pragma unroll
    for (int tn=0;tn<4;tn++) acc[tm][tn] = (f32x4)0.f;

  #pragma unroll
  for (int ks=0;ks<4;ks++) {
    v8s ah[2], bh[4], bl[4];
    #pragma unroll
    for (int tm=0;tm<2;tm++) {
      int r = row0 + wr*32 + tm*16 + low;
      ah[tm] = (r < nrows) ? *(const v8s*)(xb + (size_t)r*DD + ks*32 + quad*8) : (v8s)0;
    }
    #pragma unroll
    for (int tn=0;tn<4;tn++) {
      size_t o = ((size_t)(ks*4+quad)*128 + wc*64 + tn*16 + low)*8;
      bh[tn] = *(const v8s*)(Wh + o);
      bl[tn] = *(const v8s*)(Wl + o);
    }
    #pragma unroll
    for (int tm=0;tm<2;tm++)
      #pragma unroll
      for (int tn=0;tn<4;tn++) { MFMA2(ah[tm], bh[tn], bl[tn], acc[tm][tn]); }
  }

  #pragma unroll
  for (int tm=0;tm<2;tm++)
    #pragma unroll
    for (int i=0;i<4;i++) {
      int gr = row0 + wr*32 + tm*16 + quad*4 + i;
      if (gr >= nrows) continue;
      float sc = rowscale ? rowscale[gr] : 1.f;
      #pragma unroll
      for (int tn=0;tn<4;tn++) {
        int c = wc*64 + tn*16 + low;
        float iv = initv ? initv[c] : 0.f;
        outbf[(size_t)gr*DD + c] = (unsigned short)f2bf((acc[tm][tn][i] + iv) * sc);
      }
    }
}

// ---------------------------------------------------------------------------
// GCN aggregation on bf16-packed pre-scaled h. One wave per node; unroll 16/4
// for deep outstanding-load pipelines; fp32 accumulate.
// mode 0: outb = bf16(leaky(agg))   mode 1: outf = resid + agg (fp32)
// ---------------------------------------------------------------------------
__global__ __launch_bounds__(256)
void gcn_agg_kernel(const unsigned* __restrict__ hb, const int* __restrict__ rowptr,
                    const int* __restrict__ csr_src, const float* __restrict__ dis,
                    const float* __restrict__ bias, const float* __restrict__ resid,
                    float* __restrict__ outf, unsigned* __restrict__ outb, int mode)
{
  const int wv = threadIdx.x >> 6, lane = threadIdx.x & 63;
  const int i = blockIdx.x*4 + wv;
  if (i >= NN) return;
  unsigned hv = hb[(size_t)i*64 + lane];
  float ax = bf2f((unsigned short)(hv & 0xffff)), ay = bf2f((unsigned short)(hv >> 16));
  const int beg = rowptr[i], end = rowptr[i+1];
  int j = beg;
  for (; j + 16 <= end; j += 16) {
    unsigned v[16];
    #pragma unroll
    for (int k=0;k<16;k++) v[k] = hb[(size_t)csr_src[j+k]*64 + lane];
    #pragma unroll
    for (int k=0;k<16;k++) {
      ax += bf2f((unsigned short)(v[k] & 0xffff));
      ay += bf2f((unsigned short)(v[k] >> 16));
    }
  }
  for (; j + 4 <= end; j += 4) {
    unsigned v[4];
    #pragma unroll
    for (int k=0;k<4;k++) v[k] = hb[(size_t)csr_src[j+k]*64 + lane];
    #pragma unroll
    for (int k=0;k<4;k++) {
      ax += bf2f((unsigned short)(v[k] & 0xffff));
      ay += bf2f((unsigned short)(v[k] >> 16));
    }
  }
  for (; j < end; j++) {
    unsigned v = hb[(size_t)csr_src[j]*64 + lane];
    ax += bf2f((unsigned short)(v & 0xffff));
    ay += bf2f((unsigned short)(v >> 16));
  }
  float di = dis[i];
  ax = ax*di + bias[2*lane]; ay = ay*di + bias[2*lane+1];
  size_t o = (size_t)i*64 + lane;
  if (mode == 0) {
    unsigned pk = ((unsigned)(unsigned short)f2bf(leakyf(ay)) << 16)
                |  (unsigned)(unsigned short)f2bf(leakyf(ax));
    outb[o] = pk;
  } else {
    float2 rs = ((const float2*)resid)[o];
    float2 r; r.x = rs.x + ax; r.y = rs.y + ay;
    ((float2*)outf)[o] = r;
  }
}

// ---------------------------------------------------------------------------
// Graph setup
// ---------------------------------------------------------------------------
__global__ void count_kernel(const int* __restrict__ src, const int* __restrict__ dst,
                             int* __restrict__ cnt_src, int* __restrict__ deg_dst)
{
  int e = blockIdx.x*blockDim.x + threadIdx.x;
  if (e < NE) {
    atomicAdd(&cnt_src[src[e]], 1);
    atomicAdd(&deg_dst[dst[e]], 1);
  }
}

__global__ void nodeparams_kernel(const int* __restrict__ deg_dst, const int* __restrict__ cnt_src,
                                  float* __restrict__ dis, float* __restrict__ invcnt)
{
  int i = blockIdx.x*blockDim.x + threadIdx.x;
  if (i < NN) {
    dis[i] = rsqrtf((float)deg_dst[i] + 1.0f);
    invcnt[i] = 1.0f / fmaxf((float)cnt_src[i], 1.0f);
  }
}

__global__ void scan_kernel(const int* __restrict__ deg, int* __restrict__ rowptr,
                            int* __restrict__ nextp)
{
  const int T = 256;
  int tid = threadIdx.x;
  int chunk = (NN + T - 1) / T;
  int begin = tid*chunk, end = begin + chunk; if (end > NN) end = NN; if (begin > NN) begin = NN;
  int s = 0;
  for (int i = begin; i < end; i++) s += deg[i];
  __shared__ int ps[T];
  ps[tid] = s; __syncthreads();
  for (int off = 1; off < T; off <<= 1) {
    int v = 0;
    if (tid >= off) v = ps[tid - off];
    __syncthreads();
    if (tid >= off) ps[tid] += v;
    __syncthreads();
  }
  int base = (tid == 0) ? 0 : ps[tid-1];
  for (int i = begin; i < end; i++) { rowptr[i] = base; nextp[i] = base; base += deg[i]; }
  if (tid == T-1) rowptr[NN] = base;
}

__global__ void fill_kernel(const int* __restrict__ src, const int* __restrict__ dst,
                            int* __restrict__ nextp, int* __restrict__ csr_src)
{
  int e = blockIdx.x*blockDim.x + threadIdx.x;
  if (e < NE) {
    int pos = atomicAdd(&nextp[dst[e]], 1);
    csr_src[pos] = src[e];
  }
}

__global__ void fill_src_kernel(const int* __restrict__ src, int* __restrict__ nexts,
                                int* __restrict__ eperm, int* __restrict__ srcsorted)
{
  int e = blockIdx.x*blockDim.x + threadIdx.x;
  if (e < NE) {
    int s = src[e];
    int pos = atomicAdd(&nexts[s], 1);
    eperm[pos] = e;
    srcsorted[pos] = s;
  }
}

__global__ void addmean_kernel(float* __restrict__ hn, const float* __restrict__ nodesum,
                               const float* __restrict__ invcnt)
{
  int t = blockIdx.x*blockDim.x + threadIdx.x;
  if (t < NN*DD) hn[t] += nodesum[t] * invcnt[t >> 7];
}

// ---------------------------------------------------------------------------
// BatchNorm stats (bf16 y) + parallel fold into packed hi/lo bf16 conv2 weight
// ---------------------------------------------------------------------------
__global__ __launch_bounds__(256)
void bn_stats_kernel(const unsigned short* __restrict__ yb, float* __restrict__ sums)
{
  int col = threadIdx.x & 127, grp = threadIdx.x >> 7;
  float s = 0.f, ss = 0.f;
  for (int i = blockIdx.x*2 + grp; i < NN; i += gridDim.x*2) {
    float v = bf2f(yb[(size_t)i*DD + col]);
    s += v; ss += v*v;
  }
  __shared__ float ls[256], lss[256];
  ls[threadIdx.x] = s; lss[threadIdx.x] = ss;
  __syncthreads();
  if (grp == 0) {
    atomicAdd(&sums[col],      ls[col]  + ls[col+128]);
    atomicAdd(&sums[DD + col], lss[col] + lss[col+128]);
  }
}

// grid = 16 blocks; block b handles k in [b*8, b*8+8). cvec pre-zeroed.
__global__ __launch_bounds__(256)
void bn_fold_kernel(const float* __restrict__ sums, const float* __restrict__ g,
                    const float* __restrict__ b, const float* __restrict__ W2,
                    short* __restrict__ Wfh, short* __restrict__ Wfl,
                    float* __restrict__ cvec)
{
  __shared__ float scale_s[DD], shift_s[DD];
  int tid = threadIdx.x;
  if (tid < DD) {
    float m = sums[tid] / (float)NN;
    float var = sums[DD + tid] / (float)NN - m*m;
    float is = rsqrtf(var + LN_EPS);
    float sc = is * g[tid];
    scale_s[tid] = sc;
    shift_s[tid] = b[tid] - m * sc;
  }
  __syncthreads();
  int col = tid & 127, kh = tid >> 7;   // kh = 0..1
  float cpart = 0.f;
  #pragma unroll
  for (int kk = 0; kk < 4; kk++) {
    int k = blockIdx.x*8 + kh*4 + kk;
    float w = W2[k*DD + col];
    short2 t = f2bf2v(w * scale_s[k]);
    size_t o = ((size_t)(k >> 3)*128 + col)*8 + (k & 7);
    Wfh[o] = t.x; Wfl[o] = t.y;
    cpart += shift_s[k] * w;
  }
  atomicAdd(&cvec[col], cpart);
}

// ---------------------------------------------------------------------------
extern "C" void kernel_launch(void* const* d_in, const int* in_sizes, int n_in,
                              void* d_out, int out_size, void* d_ws, size_t ws_size,
                              hipStream_t stream)
{
  const float* node_feat = (const float*)d_in[0];
  const float* edge_feat = (const float*)d_in[1];
  const int*   edge_index = (const int*)d_in[2];
  const int* src = edge_index;
  const int* dst = edge_index + NE;

  const float* enW1 = (const float*)d_in[3];  const float* enb1 = (const float*)d_in[4];
  const float* enW2 = (const float*)d_in[5];  const float* enb2 = (const float*)d_in[6];
  const float* enW3 = (const float*)d_in[7];  const float* enb3 = (const float*)d_in[8];
  const float* enlg = (const float*)d_in[9];  const float* enlb = (const float*)d_in[10];

  const float* eeW1 = (const float*)d_in[11]; const float* eeb1 = (const float*)d_in[12];
  const float* eeW2 = (const float*)d_in[13]; const float* eeb2 = (const float*)d_in[14];
  const float* eeW3 = (const float*)d_in[15]; const float* eeb3 = (const float*)d_in[16];
  const float* eelg = (const float*)d_in[17]; const float* eelb = (const float*)d_in[18];

  const float* procW = (const float*)d_in[19];
  const float* procB = (const float*)d_in[20];
  const float* bnG   = (const float*)d_in[21];
  const float* bnB   = (const float*)d_in[22];

  const float* dW1 = (const float*)d_in[23]; const float* db1 = (const float*)d_in[24];
  const float* dW2 = (const float*)d_in[25]; const float* db2 = (const float*)d_in[26];
  const float* dW3 = (const float*)d_in[27]; const float* db3 = (const float*)d_in[28];
  const float* dlg = (const float*)d_in[29]; const float* dlb = (const float*)d_in[30];

  char* ws = (char*)d_ws;
  size_t off = 0;
  auto alloc = [&](size_t bytes) -> void* {
    void* p = ws + off;
    off = (off + bytes + 255) & ~(size_t)255;
    return p;
  };
  float* hn     = (float*)alloc((size_t)NN*DD*4);
  float* esum   = (float*)alloc((size_t)NN*DD*4);   // edge scatter-sum accumulator
  unsigned short* hbf = (unsigned short*)alloc((size_t)NN*DD*2);  // bf16 gather table
  unsigned short* ybf = (unsigned short*)alloc((size_t)NN*DD*2);  // bf16 y (BN input)
  float* dis    = (float*)alloc(NN*4);
  float* invcnt = (float*)alloc(NN*4);
  float* bnsums = (float*)alloc(3*DD*4);   // [sum, sumsq, cvec]
  float* cvec   = bnsums + 2*DD;
  int* deg    = (int*)alloc(NN*4);
  int* cnt    = (int*)alloc(NN*4);
  int* rowptr = (int*)alloc((NN+1)*4);
  int* nextp  = (int*)alloc(NN*4);
  int* srow   = (int*)alloc((NN+1)*4);
  int* nexts  = (int*)alloc(NN*4);
  int* csr    = (int*)alloc((size_t)NE*4);
  int* eperm  = (int*)alloc((size_t)NE*4);
  int* srcsorted = (int*)alloc((size_t)NE*4);
  auto allocW = [&](int kp) { return (short*)alloc((size_t)kp*128*2); };
  short *pN1h=allocW(32),  *pN1l=allocW(32);
  short *pN2h=allocW(128), *pN2l=allocW(128);
  short *pN3h=allocW(128), *pN3l=allocW(128);
  short *pE1h=allocW(32),  *pE1l=allocW(32);
  short *pE2h=allocW(128), *pE2l=allocW(128);
  short *pE3h=allocW(128), *pE3l=allocW(128);
  short *pD1h=allocW(128), *pD1l=allocW(128);
  short *pD2h=allocW(128), *pD2l=allocW(128);
  short *pD3h=allocW(128), *pD3l=allocW(128);
  short *pP0h[5], *pP0l[5];
  for (int s = 0; s < 5; s++) { pP0h[s]=allocW(128); pP0l[s]=allocW(128); }
  short *pWfh=allocW(128), *pWfl=allocW(128);

  (void)hipMemsetAsync(deg, 0, NN*4, stream);
  (void)hipMemsetAsync(cnt, 0, NN*4, stream);
  (void)hipMemsetAsync(esum, 0, (size_t)NN*DD*4, stream);

  // pack static weights
  const int G32 = (32*128+255)/256, G128 = (128*128+255)/256;
  pack_w_kernel<<<G32, 256, 0, stream>>>(enW1, pN1h, pN1l, 19, 32);
  pack_w_kernel<<<G128,256, 0, stream>>>(enW2, pN2h, pN2l, 128, 128);
  pack_w_kernel<<<G128,256, 0, stream>>>(enW3, pN3h, pN3l, 128, 128);
  pack_w_kernel<<<G32, 256, 0, stream>>>(eeW1, pE1h, pE1l, 4, 32);
  pack_w_kernel<<<G128,256, 0, stream>>>(eeW2, pE2h, pE2l, 128, 128);
  pack_w_kernel<<<G128,256, 0, stream>>>(eeW3, pE3h, pE3l, 128, 128);
  pack_w_kernel<<<G128,256, 0, stream>>>(dW1, pD1h, pD1l, 128, 128);
  pack_w_kernel<<<G128,256, 0, stream>>>(dW2, pD2h, pD2l, 128, 128);
  pack_w_kernel<<<G128,256, 0, stream>>>(dW3, pD3h, pD3l, 128, 128);
  for (int s = 0; s < 5; s++)
    pack_w_kernel<<<G128,256,0,stream>>>(procW + (size_t)(s*2)*DD*DD, pP0h[s], pP0l[s], 128, 128);

  // graph setup
  count_kernel<<<(NE+255)/256, 256, 0, stream>>>(src, dst, cnt, deg);
  nodeparams_kernel<<<(NN+255)/256, 256, 0, stream>>>(deg, cnt, dis, invcnt);
  scan_kernel<<<1, 256, 0, stream>>>(deg, rowptr, nextp);
  scan_kernel<<<1, 256, 0, stream>>>(cnt, srow, nexts);
  fill_kernel<<<(NE+255)/256, 256, 0, stream>>>(src, dst, nextp, csr);
  fill_src_kernel<<<(NE+255)/256, 256, 0, stream>>>(src, nexts, eperm, srcsorted);

  const int GN  = (NN + 127) / 128;  // 391
  const int GE  = NE / 128;          // 6250
  const int GG  = (NN + 63) / 64;    // 782
  const int GA  = (NN + 3) / 4;      // 12500

  // encoders
  mlp_mfma_kernel<19, false><<<GN, 256, 0, stream>>>(node_feat, NN,
      pN1h, pN1l, enb1, pN2h, pN2l, enb2, pN3h, pN3l, enb3, enlg, enlb, hn,
      nullptr, nullptr);
  mlp_mfma_kernel<4, true><<<GE, 256, 0, stream>>>(edge_feat, NE,
      pE1h, pE1l, eeb1, pE2h, pE2l, eeb2, pE3h, pE3l, eeb3, eelg, eelb, esum,
      srcsorted, eperm);
  addmean_kernel<<<(NN*DD+255)/256, 256, 0, stream>>>(hn, esum, invcnt);

  // processor: 5 residual (conv -> leaky -> BN -> conv) steps
  for (int s = 0; s < 5; s++) {
    const float* Wc2 = procW + (size_t)(s*2+1)*DD*DD;
    const float* b0  = procB + (size_t)(s*2+0)*DD;
    const float* b1p = procB + (size_t)(s*2+1)*DD;

    gemm_mfma_kernel<<<GG, 256, 0, stream>>>(hn, pP0h[s], pP0l[s], nullptr, dis, hbf, NN);
    gcn_agg_kernel<<<GA, 256, 0, stream>>>((const unsigned*)hbf, rowptr, csr, dis,
                                           b0, nullptr, nullptr, (unsigned*)ybf, 0);
    (void)hipMemsetAsync(bnsums, 0, 3*DD*4, stream);
    bn_stats_kernel<<<512, 256, 0, stream>>>(ybf, bnsums);
    bn_fold_kernel<<<16, 256, 0, stream>>>(bnsums, bnG + s*DD, bnB + s*DD, Wc2, pWfh, pWfl, cvec);
    gemm_bf_mfma_kernel<<<GG, 256, 0, stream>>>(ybf, pWfh, pWfl, cvec, dis, hbf, NN);
    gcn_agg_kernel<<<GA, 256, 0, stream>>>((const unsigned*)hbf, rowptr, csr, dis,
                                           b1p, hn, hn, nullptr, 1);
  }

  // decoder -> d_out (fp32)
  mlp_mfma_kernel<128, false><<<GN, 256, 0, stream>>>(hn, NN,
      pD1h, pD1l, db1, pD2h, pD2l, db2, pD3h, pD3l, db3, dlg, dlb, (float*)d_out,
      nullptr, nullptr);
}

// Round 10
// 1522.527 us; speedup vs baseline: 1.6119x; 1.0259x over previous
//
#include <hip/hip_runtime.h>

#define NN 50000
#define NE 800000
#define DD 128
#define LN_EPS 1e-5f

typedef __attribute__((ext_vector_type(8))) short v8s;    // 8 bf16
typedef __attribute__((ext_vector_type(4))) float f32x4;  // MFMA acc

__device__ __forceinline__ float leakyf(float x){ return x > 0.f ? x : 0.05f*x; }
__device__ __forceinline__ short f2bf(float f){
  unsigned u = __float_as_uint(f);
  u = (u + 0x7fffu + ((u >> 16) & 1u)) >> 16;   // RNE
  return (short)u;
}
__device__ __forceinline__ float bf2f(unsigned short h){
  return __uint_as_float(((unsigned)h) << 16);
}
// split fp32 -> {hi, lo}: hi = truncated top-16 (cheap), lo = RNE(residual).
__device__ __forceinline__ short2 f2bf2v(float v){
  unsigned u = __float_as_uint(v);
  short hi = (short)(u >> 16);
  float lo = v - __uint_as_float(u & 0xffff0000u);
  return make_short2(hi, f2bf(lo));
}

// ---------------------------------------------------------------------------
// Weight packing: fp32 W[K][128] -> bf16 hi/lo planes, [(k>>3)*128+n][k&7]
// ---------------------------------------------------------------------------
__global__ void pack_w_kernel(const float* __restrict__ W, short* __restrict__ Wh,
                              short* __restrict__ Wl, int K, int Kp)
{
  int idx = blockIdx.x*256 + threadIdx.x;
  if (idx >= Kp*128) return;
  int k = idx >> 7, n = idx & 127;
  float v = (k < K) ? W[k*128 + n] : 0.f;
  short2 t = f2bf2v(v);
  size_t o = ((size_t)(k >> 3)*128 + n)*8 + (k & 7);
  Wh[o] = t.x; Wl[o] = t.y;
}

#define NPACK 11
struct PackArgs { const float* src[NPACK]; short* dh[NPACK]; short* dl[NPACK]; };

// all-K=128 batch pack: grid (64, NPACK)
__global__ void pack_many_kernel(PackArgs pa)
{
  int m = blockIdx.y;
  int idx = blockIdx.x*256 + threadIdx.x;   // 0..16383
  int k = idx >> 7, n = idx & 127;
  float v = pa.src[m][k*128 + n];
  short2 t = f2bf2v(v);
  size_t o = ((size_t)(k >> 3)*128 + n)*8 + (k & 7);
  pa.dh[m][o] = t.x; pa.dl[m][o] = t.y;
}

// full split-split product (A has hi+lo)
#define MFMA3(ah, al, bh, bl, ac) \
  ac = __builtin_amdgcn_mfma_f32_16x16x32_bf16(al, bh, ac, 0,0,0); \
  ac = __builtin_amdgcn_mfma_f32_16x16x32_bf16(ah, bl, ac, 0,0,0); \
  ac = __builtin_amdgcn_mfma_f32_16x16x32_bf16(ah, bh, ac, 0,0,0);

// A exact-bf16 (no lo plane): 2 MFMAs
#define MFMA2(ah, bh, bl, ac) \
  ac = __builtin_amdgcn_mfma_f32_16x16x32_bf16(ah, bl, ac, 0,0,0); \
  ac = __builtin_amdgcn_mfma_f32_16x16x32_bf16(ah, bh, ac, 0,0,0);

#define SPLIT8(f0, f1, h, l) { \
  short2 t0 = f2bf2v(f0.x), t1 = f2bf2v(f0.y), t2 = f2bf2v(f0.z), t3 = f2bf2v(f0.w); \
  short2 t4 = f2bf2v(f1.x), t5 = f2bf2v(f1.y), t6 = f2bf2v(f1.z), t7 = f2bf2v(f1.w); \
  h[0]=t0.x; l[0]=t0.y; h[1]=t1.x; l[1]=t1.y; h[2]=t2.x; l[2]=t2.y; h[3]=t3.x; l[3]=t3.y; \
  h[4]=t4.x; l[4]=t4.y; h[5]=t5.x; l[5]=t5.y; h[6]=t6.x; l[6]=t6.y; h[7]=t7.x; l[7]=t7.y; }

// ---------------------------------------------------------------------------
// 3-layer MLP + LayerNorm. Layer-1 inputs and all weights hi/lo split;
// hidden activations single-bf16 (layers 2/3 use 2 MFMAs).
// SCATTER: layer-1 edge gather staged to LDS by 128 parallel threads
// (latency-parallel), seg-reduce staging in bf16 aliasing the act plane.
// ---------------------------------------------------------------------------
template<int IN_W, bool SCATTER>
__global__ __launch_bounds__(256)
void mlp_mfma_kernel(const float* __restrict__ x, int nrows,
                     const short* __restrict__ W1h, const short* __restrict__ W1l,
                     const float* __restrict__ b1,
                     const short* __restrict__ W2h, const short* __restrict__ W2l,
                     const float* __restrict__ b2,
                     const short* __restrict__ W3h, const short* __restrict__ W3l,
                     const float* __restrict__ b3,
                     const float* __restrict__ g, const float* __restrict__ bb,
                     float* __restrict__ out,
                     const int* __restrict__ sidx,   // src-sorted src values
                     const int* __restrict__ eperm)  // sorted pos -> edge id
{
  constexpr int L1K = (IN_W + 31) / 32;
  __shared__ __align__(16) short Hh[128*136];   // act plane; reused (stride 132) as bf16 seg buffer
  __shared__ float lnS[128][2], lnQ[128][2];
  __shared__ int sidx_s[128];
  __shared__ __align__(16) float4 xstage[SCATTER ? 128 : 1];

  const int tid  = threadIdx.x;
  const int lane = tid & 63, wave = tid >> 6;
  const int wr = wave >> 1, wc = wave & 1;
  const int quad = lane >> 4, low = lane & 15;
  const int row0 = blockIdx.x * 128;

  if (SCATTER) {
    // 128 parallel scattered gathers -> LDS stage (latency overlapped)
    if (tid < 128) {
      int e = eperm[row0 + tid];           // NE % 128 == 0
      xstage[tid] = ((const float4*)x)[e];
      sidx_s[tid] = sidx[row0 + tid];
    }
    __syncthreads();
  }

  f32x4 acc[4][4];

  // ---------------- layer 1 (hi/lo A) ----------------
  #pragma unroll
  for (int tm=0;tm<4;tm++)
    #pragma unroll
    for (int tn=0;tn<4;tn++) acc[tm][tn] = (f32x4)0.f;

  for (int ks = 0; ks < L1K; ks++) {
    v8s ah[4], al[4], bh[4], bl[4];
    #pragma unroll
    for (int tm=0;tm<4;tm++) {
      int lr = wr*64 + tm*16 + low;
      v8s h = (v8s)0, l = (v8s)0;
      if (SCATTER && IN_W == 4) {
        if (quad == 0) {
          float4 f = xstage[lr];
          short2 t0 = f2bf2v(f.x), t1 = f2bf2v(f.y), t2 = f2bf2v(f.z), t3 = f2bf2v(f.w);
          h[0]=t0.x; l[0]=t0.y; h[1]=t1.x; l[1]=t1.y;
          h[2]=t2.x; l[2]=t2.y; h[3]=t3.x; l[3]=t3.y;
        }
      } else if (IN_W % 32 == 0) {
        int r = row0 + lr;
        if (r < nrows) {
          const float* p = x + (size_t)r*IN_W + ks*32 + quad*8;
          float4 f0 = *(const float4*)p;
          float4 f1 = *(const float4*)(p + 4);
          SPLIT8(f0, f1, h, l);
        }
      } else {
        int r = row0 + lr;
        #pragma unroll
        for (int j=0;j<8;j++) {
          int k = ks*32 + quad*8 + j;
          if (k < IN_W && r < nrows) {
            short2 t = f2bf2v(x[(size_t)r*IN_W + k]);
            h[j] = t.x; l[j] = t.y;
          }
        }
      }
      ah[tm] = h; al[tm] = l;
    }
    #pragma unroll
    for (int tn=0;tn<4;tn++) {
      size_t o = ((size_t)(ks*4+quad)*128 + wc*64 + tn*16 + low)*8;
      bh[tn] = *(const v8s*)(W1h + o);
      bl[tn] = *(const v8s*)(W1l + o);
    }
    #pragma unroll
    for (int tm=0;tm<4;tm++)
      #pragma unroll
      for (int tn=0;tn<4;tn++) { MFMA3(ah[tm], al[tm], bh[tn], bl[tn], acc[tm][tn]); }
  }
  #pragma unroll
  for (int tn=0;tn<4;tn++) {
    float bv = b1[wc*64 + tn*16 + low];
    #pragma unroll
    for (int tm=0;tm<4;tm++)
      #pragma unroll
      for (int i=0;i<4;i++) {
        int idx = (wr*64+tm*16+quad*4+i)*136 + wc*64+tn*16+low;
        Hh[idx] = f2bf(leakyf(acc[tm][tn][i] + bv));
      }
  }
  __syncthreads();

  // ---------------- layer 2 (bf16 A from LDS, 2 MFMAs) ----------------
  #pragma unroll
  for (int tm=0;tm<4;tm++)
    #pragma unroll
    for (int tn=0;tn<4;tn++) acc[tm][tn] = (f32x4)0.f;
  #pragma unroll
  for (int ks=0;ks<4;ks++) {
    v8s ah[4], bh[4], bl[4];
    #pragma unroll
    for (int tm=0;tm<4;tm++)
      ah[tm] = *(const v8s*)&Hh[(wr*64+tm*16+low)*136 + ks*32 + quad*8];
    #pragma unroll
    for (int tn=0;tn<4;tn++) {
      size_t o = ((size_t)(ks*4+quad)*128 + wc*64 + tn*16 + low)*8;
      bh[tn] = *(const v8s*)(W2h + o);
      bl[tn] = *(const v8s*)(W2l + o);
    }
    #pragma unroll
    for (int tm=0;tm<4;tm++)
      #pragma unroll
      for (int tn=0;tn<4;tn++) { MFMA2(ah[tm], bh[tn], bl[tn], acc[tm][tn]); }
  }
  __syncthreads();
  #pragma unroll
  for (int tn=0;tn<4;tn++) {
    float bv = b2[wc*64 + tn*16 + low];
    #pragma unroll
    for (int tm=0;tm<4;tm++)
      #pragma unroll
      for (int i=0;i<4;i++) {
        int idx = (wr*64+tm*16+quad*4+i)*136 + wc*64+tn*16+low;
        Hh[idx] = f2bf(leakyf(acc[tm][tn][i] + bv));
      }
  }
  __syncthreads();

  // ---------------- layer 3 (bf16 A from LDS, 2 MFMAs) ----------------
  #pragma unroll
  for (int tm=0;tm<4;tm++)
    #pragma unroll
    for (int tn=0;tn<4;tn++) acc[tm][tn] = (f32x4)0.f;
  #pragma unroll
  for (int ks=0;ks<4;ks++) {
    v8s ah[4], bh[4], bl[4];
    #pragma unroll
    for (int tm=0;tm<4;tm++)
      ah[tm] = *(const v8s*)&Hh[(wr*64+tm*16+low)*136 + ks*32 + quad*8];
    #pragma unroll
    for (int tn=0;tn<4;tn++) {
      size_t o = ((size_t)(ks*4+quad)*128 + wc*64 + tn*16 + low)*8;
      bh[tn] = *(const v8s*)(W3h + o);
      bl[tn] = *(const v8s*)(W3l + o);
    }
    #pragma unroll
    for (int tm=0;tm<4;tm++)
      #pragma unroll
      for (int tn=0;tn<4;tn++) { MFMA2(ah[tm], bh[tn], bl[tn], acc[tm][tn]); }
  }
  #pragma unroll
  for (int tn=0;tn<4;tn++) {
    float bv = b3[wc*64 + tn*16 + low];
    #pragma unroll
    for (int tm=0;tm<4;tm++)
      #pragma unroll
      for (int i=0;i<4;i++) acc[tm][tn][i] += bv;
  }

  // ---------------- fused LayerNorm ----------------
  #pragma unroll
  for (int tm=0;tm<4;tm++)
    #pragma unroll
    for (int i=0;i<4;i++) {
      float s = acc[tm][0][i] + acc[tm][1][i] + acc[tm][2][i] + acc[tm][3][i];
      float q = acc[tm][0][i]*acc[tm][0][i] + acc[tm][1][i]*acc[tm][1][i]
              + acc[tm][2][i]*acc[tm][2][i] + acc[tm][3][i]*acc[tm][3][i];
      s += __shfl_xor(s, 1); q += __shfl_xor(q, 1);
      s += __shfl_xor(s, 2); q += __shfl_xor(q, 2);
      s += __shfl_xor(s, 4); q += __shfl_xor(q, 4);
      s += __shfl_xor(s, 8); q += __shfl_xor(q, 8);
      if (low == tm*4 + i) {
        int r = wr*64 + tm*16 + quad*4 + i;
        lnS[r][wc] = s; lnQ[r][wc] = q;
      }
    }
  __syncthreads();   // all layer-3 H reads done (act-plane reuse below is safe)

  float g4[4], bb4[4];
  #pragma unroll
  for (int tn=0;tn<4;tn++) { int c = wc*64+tn*16+low; g4[tn] = g[c]; bb4[tn] = bb[c]; }

  #pragma unroll
  for (int tm=0;tm<4;tm++)
    #pragma unroll
    for (int i=0;i<4;i++) {
      int r = wr*64 + tm*16 + quad*4 + i;
      float s = lnS[r][0] + lnS[r][1];
      float q = lnQ[r][0] + lnQ[r][1];
      float m = s * (1.f/128.f);
      float var = q * (1.f/128.f) - m*m;
      float rs = rsqrtf(var + LN_EPS);
      int gr = row0 + r;
      if (!SCATTER && gr >= nrows) continue;
      #pragma unroll
      for (int tn=0;tn<4;tn++) {
        float v = (acc[tm][tn][i] - m) * rs * g4[tn] + bb4[tn];
        int c = wc*64 + tn*16 + low;
        if (SCATTER) Hh[r*132 + c] = f2bf(v);     // bf16 stage for seg-reduce
        else         out[(size_t)gr*DD + c] = v;
      }
    }

  if (SCATTER) {
    __syncthreads();
    int col  = tid & 127;
    int rbeg = (tid >> 7) * 64, rend = rbeg + 64;
    float accv = bf2f((unsigned short)Hh[rbeg*132 + col]);
    int cur = sidx_s[rbeg];
    for (int r = rbeg + 1; r < rend; r++) {
      int sv = sidx_s[r];
      float hv = bf2f((unsigned short)Hh[r*132 + col]);
      if (sv != cur) {
        atomicAdd(&out[(size_t)cur*DD + col], accv);
        accv = hv; cur = sv;
      } else accv += hv;
    }
    atomicAdd(&out[(size_t)cur*DD + col], accv);
  }
}

// ---------------------------------------------------------------------------
// outbf[r] = bf16((x[r] @ W + initv) * rowscale[r])  — fp32 input (split, 3 MFMA)
// ---------------------------------------------------------------------------
__global__ __launch_bounds__(256)
void gemm_mfma_kernel(const float* __restrict__ x,
                      const short* __restrict__ Wh, const short* __restrict__ Wl,
                      const float* __restrict__ initv, const float* __restrict__ rowscale,
                      unsigned short* __restrict__ outbf, int nrows)
{
  const int tid  = threadIdx.x;
  const int lane = tid & 63, wave = tid >> 6;
  const int wr = wave >> 1, wc = wave & 1;
  const int quad = lane >> 4, low = lane & 15;
  const int row0 = blockIdx.x * 64;

  f32x4 acc[2][4];
  #pragma unroll
  for (int tm=0;tm<2;tm++)
    #pragma unroll
    for (int tn=0;tn<4;tn++) acc[tm][tn] = (f32x4)0.f;

  #pragma unroll
  for (int ks=0;ks<4;ks++) {
    v8s ah[2], al[2], bh[4], bl[4];
    #pragma unroll
    for (int tm=0;tm<2;tm++) {
      int r = row0 + wr*32 + tm*16 + low;
      v8s h = (v8s)0, l = (v8s)0;
      if (r < nrows) {
        const float* p = x + (size_t)r*DD + ks*32 + quad*8;
        float4 f0 = *(const float4*)p;
        float4 f1 = *(const float4*)(p + 4);
        SPLIT8(f0, f1, h, l);
      }
      ah[tm] = h; al[tm] = l;
    }
    #pragma unroll
    for (int tn=0;tn<4;tn++) {
      size_t o = ((size_t)(ks*4+quad)*128 + wc*64 + tn*16 + low)*8;
      bh[tn] = *(const v8s*)(Wh + o);
      bl[tn] = *(const v8s*)(Wl + o);
    }
    #pragma unroll
    for (int tm=0;tm<2;tm++)
      #pragma unroll
      for (int tn=0;tn<4;tn++) { MFMA3(ah[tm], al[tm], bh[tn], bl[tn], acc[tm][tn]); }
  }

  #pragma unroll
  for (int tm=0;tm<2;tm++)
    #pragma unroll
    for (int i=0;i<4;i++) {
      int gr = row0 + wr*32 + tm*16 + quad*4 + i;
      if (gr >= nrows) continue;
      float sc = rowscale ? rowscale[gr] : 1.f;
      #pragma unroll
      for (int tn=0;tn<4;tn++) {
        int c = wc*64 + tn*16 + low;
        float iv = initv ? initv[c] : 0.f;
        outbf[(size_t)gr*DD + c] = (unsigned short)f2bf((acc[tm][tn][i] + iv) * sc);
      }
    }
}

// ---------------------------------------------------------------------------
// Same but bf16 input (exact, 2 MFMA, 16 B/lane A-loads) — conv2 on y.
// ---------------------------------------------------------------------------
__global__ __launch_bounds__(256)
void gemm_bf_mfma_kernel(const unsigned short* __restrict__ xb,
                         const short* __restrict__ Wh, const short* __restrict__ Wl,
                         const float* __restrict__ initv, const float* __restrict__ rowscale,
                         unsigned short* __restrict__ outbf, int nrows)
{
  const int tid  = threadIdx.x;
  const int lane = tid & 63, wave = tid >> 6;
  const int wr = wave >> 1, wc = wave & 1;
  const int quad = lane >> 4, low = lane & 15;
  const int row0 = blockIdx.x * 64;

  f32x4 acc[2][4];
  #pragma unroll
  for (int tm=0;tm<2;tm++)
    #pragma unroll
    for (int tn=0;tn<4;tn++) acc[tm][tn] = (f32x4)0.f;

  #pragma unroll
  for (int ks=0;ks<4;ks++) {
    v8s ah[2], bh[4], bl[4];
    #pragma unroll
    for (int tm=0;tm<2;tm++) {
      int r = row0 + wr*32 + tm*16 + low;
      ah[tm] = (r < nrows) ? *(const v8s*)(xb + (size_t)r*DD + ks*32 + quad*8) : (v8s)0;
    }
    #pragma unroll
    for (int tn=0;tn<4;tn++) {
      size_t o = ((size_t)(ks*4+quad)*128 + wc*64 + tn*16 + low)*8;
      bh[tn] = *(const v8s*)(Wh + o);
      bl[tn] = *(const v8s*)(Wl + o);
    }
    #pragma unroll
    for (int tm=0;tm<2;tm++)
      #pragma unroll
      for (int tn=0;tn<4;tn++) { MFMA2(ah[tm], bh[tn], bl[tn], acc[tm][tn]); }
  }

  #pragma unroll
  for (int tm=0;tm<2;tm++)
    #pragma unroll
    for (int i=0;i<4;i++) {
      int gr = row0 + wr*32 + tm*16 + quad*4 + i;
      if (gr >= nrows) continue;
      float sc = rowscale ? rowscale[gr] : 1.f;
      #pragma unroll
      for (int tn=0;tn<4;tn++) {
        int c = wc*64 + tn*16 + low;
        float iv = initv ? initv[c] : 0.f;
        outbf[(size_t)gr*DD + c] = (unsigned short)f2bf((acc[tm][tn][i] + iv) * sc);
      }
    }
}

// ---------------------------------------------------------------------------
// GCN aggregation on bf16-packed pre-scaled h. One wave per node; unroll 16/4.
// mode 0: outb = bf16(leaky(agg))   mode 1: outf = resid + agg (fp32)
// ---------------------------------------------------------------------------
__global__ __launch_bounds__(256)
void gcn_agg_kernel(const unsigned* __restrict__ hb, const int* __restrict__ rowptr,
                    const int* __restrict__ csr_src, const float* __restrict__ dis,
                    const float* __restrict__ bias, const float* __restrict__ resid,
                    float* __restrict__ outf, unsigned* __restrict__ outb, int mode)
{
  const int wv = threadIdx.x >> 6, lane = threadIdx.x & 63;
  const int i = blockIdx.x*4 + wv;
  if (i >= NN) return;
  unsigned hv = hb[(size_t)i*64 + lane];
  float ax = bf2f((unsigned short)(hv & 0xffff)), ay = bf2f((unsigned short)(hv >> 16));
  const int beg = rowptr[i], end = rowptr[i+1];
  int j = beg;
  for (; j + 16 <= end; j += 16) {
    unsigned v[16];
    #pragma unroll
    for (int k=0;k<16;k++) v[k] = hb[(size_t)csr_src[j+k]*64 + lane];
    #pragma unroll
    for (int k=0;k<16;k++) {
      ax += bf2f((unsigned short)(v[k] & 0xffff));
      ay += bf2f((unsigned short)(v[k] >> 16));
    }
  }
  for (; j + 4 <= end; j += 4) {
    unsigned v[4];
    #pragma unroll
    for (int k=0;k<4;k++) v[k] = hb[(size_t)csr_src[j+k]*64 + lane];
    #pragma unroll
    for (int k=0;k<4;k++) {
      ax += bf2f((unsigned short)(v[k] & 0xffff));
      ay += bf2f((unsigned short)(v[k] >> 16));
    }
  }
  for (; j < end; j++) {
    unsigned v = hb[(size_t)csr_src[j]*64 + lane];
    ax += bf2f((unsigned short)(v & 0xffff));
    ay += bf2f((unsigned short)(v >> 16));
  }
  float di = dis[i];
  ax = ax*di + bias[2*lane]; ay = ay*di + bias[2*lane+1];
  size_t o = (size_t)i*64 + lane;
  if (mode == 0) {
    unsigned pk = ((unsigned)(unsigned short)f2bf(leakyf(ay)) << 16)
                |  (unsigned)(unsigned short)f2bf(leakyf(ax));
    outb[o] = pk;
  } else {
    float2 rs = ((const float2*)resid)[o];
    float2 r; r.x = rs.x + ax; r.y = rs.y + ay;
    ((float2*)outf)[o] = r;
  }
}

// ---------------------------------------------------------------------------
// Graph setup
// ---------------------------------------------------------------------------
__global__ void count_kernel(const int* __restrict__ src, const int* __restrict__ dst,
                             int* __restrict__ cnt_src, int* __restrict__ deg_dst)
{
  int e = blockIdx.x*blockDim.x + threadIdx.x;
  if (e < NE) {
    atomicAdd(&cnt_src[src[e]], 1);
    atomicAdd(&deg_dst[dst[e]], 1);
  }
}

__global__ void nodeparams_kernel(const int* __restrict__ deg_dst, const int* __restrict__ cnt_src,
                                  float* __restrict__ dis, float* __restrict__ invcnt)
{
  int i = blockIdx.x*blockDim.x + threadIdx.x;
  if (i < NN) {
    dis[i] = rsqrtf((float)deg_dst[i] + 1.0f);
    invcnt[i] = 1.0f / fmaxf((float)cnt_src[i], 1.0f);
  }
}

// two independent single-block scans: block 0 = (a0->r0,n0), block 1 = (a1->r1,n1)
__global__ void scan2_kernel(const int* __restrict__ a0, int* __restrict__ r0, int* __restrict__ n0,
                             const int* __restrict__ a1, int* __restrict__ r1, int* __restrict__ n1)
{
  const int* a = blockIdx.x ? a1 : a0;
  int* r = blockIdx.x ? r1 : r0;
  int* n = blockIdx.x ? n1 : n0;
  const int T = 256;
  int tid = threadIdx.x;
  int chunk = (NN + T - 1) / T;
  int begin = tid*chunk, end = begin + chunk; if (end > NN) end = NN; if (begin > NN) begin = NN;
  int s = 0;
  for (int i = begin; i < end; i++) s += a[i];
  __shared__ int ps[T];
  ps[tid] = s; __syncthreads();
  for (int off = 1; off < T; off <<= 1) {
    int v = 0;
    if (tid >= off) v = ps[tid - off];
    __syncthreads();
    if (tid >= off) ps[tid] += v;
    __syncthreads();
  }
  int base = (tid == 0) ? 0 : ps[tid-1];
  for (int i = begin; i < end; i++) { r[i] = base; n[i] = base; base += a[i]; }
  if (tid == T-1) r[NN] = base;
}

__global__ void fill_kernel(const int* __restrict__ src, const int* __restrict__ dst,
                            int* __restrict__ nextp, int* __restrict__ csr_src)
{
  int e = blockIdx.x*blockDim.x + threadIdx.x;
  if (e < NE) {
    int pos = atomicAdd(&nextp[dst[e]], 1);
    csr_src[pos] = src[e];
  }
}

__global__ void fill_src_kernel(const int* __restrict__ src, int* __restrict__ nexts,
                                int* __restrict__ eperm, int* __restrict__ srcsorted)
{
  int e = blockIdx.x*blockDim.x + threadIdx.x;
  if (e < NE) {
    int s = src[e];
    int pos = atomicAdd(&nexts[s], 1);
    eperm[pos] = e;
    srcsorted[pos] = s;
  }
}

__global__ void addmean_kernel(float* __restrict__ hn, const float* __restrict__ nodesum,
                               const float* __restrict__ invcnt)
{
  int t = blockIdx.x*blockDim.x + threadIdx.x;
  if (t < NN*DD) hn[t] += nodesum[t] * invcnt[t >> 7];
}

// ---------------------------------------------------------------------------
// BatchNorm stats (bf16 y) + parallel fold into packed hi/lo bf16 conv2 weight
// ---------------------------------------------------------------------------
__global__ __launch_bounds__(256)
void bn_stats_kernel(const unsigned short* __restrict__ yb, float* __restrict__ sums)
{
  int col = threadIdx.x & 127, grp = threadIdx.x >> 7;
  float s = 0.f, ss = 0.f;
  for (int i = blockIdx.x*2 + grp; i < NN; i += gridDim.x*2) {
    float v = bf2f(yb[(size_t)i*DD + col]);
    s += v; ss += v*v;
  }
  __shared__ float ls[256], lss[256];
  ls[threadIdx.x] = s; lss[threadIdx.x] = ss;
  __syncthreads();
  if (grp == 0) {
    atomicAdd(&sums[col],      ls[col]  + ls[col+128]);
    atomicAdd(&sums[DD + col], lss[col] + lss[col+128]);
  }
}

// grid = 16 blocks; block b handles k in [b*8, b*8+8). cvec pre-zeroed.
__global__ __launch_bounds__(256)
void bn_fold_kernel(const float* __restrict__ sums, const float* __restrict__ g,
                    const float* __restrict__ b, const float* __restrict__ W2,
                    short* __restrict__ Wfh, short* __restrict__ Wfl,
                    float* __restrict__ cvec)
{
  __shared__ float scale_s[DD], shift_s[DD];
  int tid = threadIdx.x;
  if (tid < DD) {
    float m = sums[tid] / (float)NN;
    float var = sums[DD + tid] / (float)NN - m*m;
    float is = rsqrtf(var + LN_EPS);
    float sc = is * g[tid];
    scale_s[tid] = sc;
    shift_s[tid] = b[tid] - m * sc;
  }
  __syncthreads();
  int col = tid & 127, kh = tid >> 7;   // kh = 0..1
  float cpart = 0.f;
  #pragma unroll
  for (int kk = 0; kk < 4; kk++) {
    int k = blockIdx.x*8 + kh*4 + kk;
    float w = W2[k*DD + col];
    short2 t = f2bf2v(w * scale_s[k]);
    size_t o = ((size_t)(k >> 3)*128 + col)*8 + (k & 7);
    Wfh[o] = t.x; Wfl[o] = t.y;
    cpart += shift_s[k] * w;
  }
  atomicAdd(&cvec[col], cpart);
}

// ---------------------------------------------------------------------------
extern "C" void kernel_launch(void* const* d_in, const int* in_sizes, int n_in,
                              void* d_out, int out_size, void* d_ws, size_t ws_size,
                              hipStream_t stream)
{
  const float* node_feat = (const float*)d_in[0];
  const float* edge_feat = (const float*)d_in[1];
  const int*   edge_index = (const int*)d_in[2];
  const int* src = edge_index;
  const int* dst = edge_index + NE;

  const float* enW1 = (const float*)d_in[3];  const float* enb1 = (const float*)d_in[4];
  const float* enW2 = (const float*)d_in[5];  const float* enb2 = (const float*)d_in[6];
  const float* enW3 = (const float*)d_in[7];  const float* enb3 = (const float*)d_in[8];
  const float* enlg = (const float*)d_in[9];  const float* enlb = (const float*)d_in[10];

  const float* eeW1 = (const float*)d_in[11]; const float* eeb1 = (const float*)d_in[12];
  const float* eeW2 = (const float*)d_in[13]; const float* eeb2 = (const float*)d_in[14];
  const float* eeW3 = (const float*)d_in[15]; const float* eeb3 = (const float*)d_in[16];
  const float* eelg = (const float*)d_in[17]; const float* eelb = (const float*)d_in[18];

  const float* procW = (const float*)d_in[19];
  const float* procB = (const float*)d_in[20];
  const float* bnG   = (const float*)d_in[21];
  const float* bnB   = (const float*)d_in[22];

  const float* dW1 = (const float*)d_in[23]; const float* db1 = (const float*)d_in[24];
  const float* dW2 = (const float*)d_in[25]; const float* db2 = (const float*)d_in[26];
  const float* dW3 = (const float*)d_in[27]; const float* db3 = (const float*)d_in[28];
  const float* dlg = (const float*)d_in[29]; const float* dlb = (const float*)d_in[30];

  char* ws = (char*)d_ws;
  size_t off = 0;
  auto alloc = [&](size_t bytes) -> void* {
    void* p = ws + off;
    off = (off + bytes + 255) & ~(size_t)255;
    return p;
  };
  float* hn     = (float*)alloc((size_t)NN*DD*4);
  float* esum   = (float*)alloc((size_t)NN*DD*4);   // edge scatter-sum accumulator
  unsigned short* hbf = (unsigned short*)alloc((size_t)NN*DD*2);  // bf16 gather table
  unsigned short* ybf = (unsigned short*)alloc((size_t)NN*DD*2);  // bf16 y (BN input)
  float* dis    = (float*)alloc(NN*4);
  float* invcnt = (float*)alloc(NN*4);
  float* bnsums = (float*)alloc(3*DD*4);   // [sum, sumsq, cvec]
  float* cvec   = bnsums + 2*DD;
  int* deg    = (int*)alloc(NN*4);
  int* cnt    = (int*)alloc(NN*4);
  int* rowptr = (int*)alloc((NN+1)*4);
  int* nextp  = (int*)alloc(NN*4);
  int* srow   = (int*)alloc((NN+1)*4);
  int* nexts  = (int*)alloc(NN*4);
  int* csr    = (int*)alloc((size_t)NE*4);
  int* eperm  = (int*)alloc((size_t)NE*4);
  int* srcsorted = (int*)alloc((size_t)NE*4);
  auto allocW = [&](int kp) { return (short*)alloc((size_t)kp*128*2); };
  short *pN1h=allocW(32),  *pN1l=allocW(32);
  short *pN2h=allocW(128), *pN2l=allocW(128);
  short *pN3h=allocW(128), *pN3l=allocW(128);
  short *pE1h=allocW(32),  *pE1l=allocW(32);
  short *pE2h=allocW(128), *pE2l=allocW(128);
  short *pE3h=allocW(128), *pE3l=allocW(128);
  short *pD1h=allocW(128), *pD1l=allocW(128);
  short *pD2h=allocW(128), *pD2l=allocW(128);
  short *pD3h=allocW(128), *pD3l=allocW(128);
  short *pP0h[5], *pP0l[5];
  for (int s = 0; s < 5; s++) { pP0h[s]=allocW(128); pP0l[s]=allocW(128); }
  short *pWfh=allocW(128), *pWfl=allocW(128);

  (void)hipMemsetAsync(deg, 0, NN*4, stream);
  (void)hipMemsetAsync(cnt, 0, NN*4, stream);
  (void)hipMemsetAsync(esum, 0, (size_t)NN*DD*4, stream);

  // pack static weights: 11 K=128 mats in one launch + 2 small ones
  PackArgs pa;
  const float* s128[NPACK] = { enW2, enW3, eeW2, eeW3, dW1, dW2, dW3,
                               procW + 0*(size_t)DD*DD*2, procW + 1*(size_t)DD*DD*2,
                               procW + 2*(size_t)DD*DD*2, procW + 3*(size_t)DD*DD*2 };
  short* d128h[NPACK] = { pN2h, pN3h, pE2h, pE3h, pD1h, pD2h, pD3h, pP0h[0], pP0h[1], pP0h[2], pP0h[3] };
  short* d128l[NPACK] = { pN2l, pN3l, pE2l, pE3l, pD1l, pD2l, pD3l, pP0l[0], pP0l[1], pP0l[2], pP0l[3] };
  for (int m = 0; m < NPACK; m++) { pa.src[m]=s128[m]; pa.dh[m]=d128h[m]; pa.dl[m]=d128l[m]; }
  pack_many_kernel<<<dim3(64, NPACK), 256, 0, stream>>>(pa);
  const int G32 = (32*128+255)/256, G128 = (128*128+255)/256;
  pack_w_kernel<<<G32, 256, 0, stream>>>(enW1, pN1h, pN1l, 19, 32);
  pack_w_kernel<<<G32, 256, 0, stream>>>(eeW1, pE1h, pE1l, 4, 32);
  pack_w_kernel<<<G128,256, 0, stream>>>(procW + 4*(size_t)DD*DD*2, pP0h[4], pP0l[4], 128, 128);

  // graph setup
  count_kernel<<<(NE+255)/256, 256, 0, stream>>>(src, dst, cnt, deg);
  nodeparams_kernel<<<(NN+255)/256, 256, 0, stream>>>(deg, cnt, dis, invcnt);
  scan2_kernel<<<2, 256, 0, stream>>>(deg, rowptr, nextp, cnt, srow, nexts);
  fill_kernel<<<(NE+255)/256, 256, 0, stream>>>(src, dst, nextp, csr);
  fill_src_kernel<<<(NE+255)/256, 256, 0, stream>>>(src, nexts, eperm, srcsorted);

  const int GN  = (NN + 127) / 128;  // 391
  const int GE  = NE / 128;          // 6250
  const int GG  = (NN + 63) / 64;    // 782
  const int GA  = (NN + 3) / 4;      // 12500

  // encoders
  mlp_mfma_kernel<19, false><<<GN, 256, 0, stream>>>(node_feat, NN,
      pN1h, pN1l, enb1, pN2h, pN2l, enb2, pN3h, pN3l, enb3, enlg, enlb, hn,
      nullptr, nullptr);
  mlp_mfma_kernel<4, true><<<GE, 256, 0, stream>>>(edge_feat, NE,
      pE1h, pE1l, eeb1, pE2h, pE2l, eeb2, pE3h, pE3l, eeb3, eelg, eelb, esum,
      srcsorted, eperm);
  addmean_kernel<<<(NN*DD+255)/256, 256, 0, stream>>>(hn, esum, invcnt);

  // processor: 5 residual (conv -> leaky -> BN -> conv) steps
  for (int s = 0; s < 5; s++) {
    const float* Wc2 = procW + (size_t)(s*2+1)*DD*DD;
    const float* b0  = procB + (size_t)(s*2+0)*DD;
    const float* b1p = procB + (size_t)(s*2+1)*DD;

    gemm_mfma_kernel<<<GG, 256, 0, stream>>>(hn, pP0h[s], pP0l[s], nullptr, dis, hbf, NN);
    gcn_agg_kernel<<<GA, 256, 0, stream>>>((const unsigned*)hbf, rowptr, csr, dis,
                                           b0, nullptr, nullptr, (unsigned*)ybf, 0);
    (void)hipMemsetAsync(bnsums, 0, 3*DD*4, stream);
    bn_stats_kernel<<<512, 256, 0, stream>>>(ybf, bnsums);
    bn_fold_kernel<<<16, 256, 0, stream>>>(bnsums, bnG + s*DD, bnB + s*DD, Wc2, pWfh, pWfl, cvec);
    gemm_bf_mfma_kernel<<<GG, 256, 0, stream>>>(ybf, pWfh, pWfl, cvec, dis, hbf, NN);
    gcn_agg_kernel<<<GA, 256, 0, stream>>>((const unsigned*)hbf, rowptr, csr, dis,
                                           b1p, hn, hn, nullptr, 1);
  }

  // decoder -> d_out (fp32)
  mlp_mfma_kernel<128, false><<<GN, 256, 0, stream>>>(hn, NN,
      pD1h, pD1l, db1, pD2h, pD2l, db2, pD3h, pD3l, db3, dlg, dlb, (float*)d_out,
      nullptr, nullptr);
}